// Round 1
// baseline (1162.308 us; speedup 1.0000x reference)
//
#include <hip/hip_runtime.h>
#include <math.h>

#define B_ 2
#define S_ 2048
#define D_ 1024
#define H_ 16
#define G_ 4
#define HPG_ 4
#define HD_ 64

typedef float fvec4 __attribute__((ext_vector_type(4)));

// ---------------- prep: pooled K/V weights + rope tables ----------------
// mean over heads commutes with projection AND with rope (rope coeffs are
// head-independent), so K/V projections shrink to 256 output dims.
__global__ __launch_bounds__(256)
void prep_kernel(const float* __restrict__ Wk, const float* __restrict__ Wv,
                 float* __restrict__ wkm, float* __restrict__ wvm,
                 float* __restrict__ cost, float* __restrict__ sint)
{
    int idx = blockIdx.x * 256 + threadIdx.x;
    if (idx < G_*HD_*D_) {
        int c  = idx & (D_ - 1);
        int rd = idx >> 10;            // g*HD + d
        int g  = rd >> 6, d = rd & 63;
        float sk = 0.f, sv = 0.f;
        #pragma unroll
        for (int p = 0; p < HPG_; ++p) {
            int row = (g*HPG_ + p)*HD_ + d;
            sk += Wk[(size_t)row*D_ + c];
            sv += Wv[(size_t)row*D_ + c];
        }
        wkm[idx] = sk * 0.25f;
        wvm[idx] = sv * 0.25f;
    }
    if (idx < S_*32) {
        int s = idx >> 5, f = idx & 31;
        float inv = 1.0f / powf(10000.0f, (float)f * (1.0f/32.0f));
        float fr  = (float)s * inv;
        cost[idx] = cosf(fr);
        sint[idx] = sinf(fr);
    }
}

// ---------------- NT GEMM: C = A(MxK) * B(NxK)^T, 64x64 tile, 4x4 micro ----
// mode 0: plain -> outp[row*N + col]                       (O-projection)
// mode 1: rope + head permute -> qr[b][h'][s][dd]          (Q projection)
// mode 2: rope -> kr[b][g][s][dd]                          (K projection)
// mode 3: plain -> vr[b][g][s][dd]                         (V projection)
__global__ __launch_bounds__(256)
void gemm_nt(const float* __restrict__ A, const float* __restrict__ Bm,
             float* __restrict__ outp, int N, int K, int mode,
             const float* __restrict__ cost, const float* __restrict__ sint)
{
    __shared__ float As[16][68];   // [k][row], +4 pad: conflict-free fvec4 reads
    __shared__ float Bs[16][68];
    const int nb = N >> 6;
    const int bx = blockIdx.x % nb;
    const int by = blockIdx.x / nb;
    const int t  = threadIdx.x;
    const int tx = t & 15, ty = t >> 4;
    const float* Ab = A  + (size_t)by*64*K;
    const float* Bb = Bm + (size_t)bx*64*K;
    float acc[4][4] = {};
    for (int k0 = 0; k0 < K; k0 += 16) {
        __syncthreads();
        #pragma unroll
        for (int i = 0; i < 4; ++i) {
            As[tx][ty + 16*i] = Ab[(size_t)(ty + 16*i)*K + k0 + tx];
            Bs[tx][ty + 16*i] = Bb[(size_t)(ty + 16*i)*K + k0 + tx];
        }
        __syncthreads();
        #pragma unroll
        for (int k = 0; k < 16; ++k) {
            fvec4 a = *(const fvec4*)&As[k][4*ty];
            fvec4 b = *(const fvec4*)&Bs[k][4*tx];
            #pragma unroll
            for (int i = 0; i < 4; ++i)
                #pragma unroll
                for (int j = 0; j < 4; ++j)
                    acc[i][j] = fmaf(a[i], b[j], acc[i][j]);
        }
    }

    if (mode == 0) {
        #pragma unroll
        for (int i = 0; i < 4; ++i) {
            int row = by*64 + 4*ty + i;
            fvec4 v;
            #pragma unroll
            for (int j = 0; j < 4; ++j) v[j] = acc[i][j];
            *(fvec4*)&outp[(size_t)row*N + bx*64 + 4*tx] = v;
        }
        return;
    }
    if (mode == 3) {
        #pragma unroll
        for (int i = 0; i < 4; ++i) {
            int row = by*64 + 4*ty + i;
            int b = row >> 11, s = row & (S_ - 1);
            fvec4 v;
            #pragma unroll
            for (int j = 0; j < 4; ++j) v[j] = acc[i][j];
            *(fvec4*)&outp[(((size_t)b*G_ + bx)*S_ + s)*HD_ + 4*tx] = v;
        }
        return;
    }
    // rope modes: partner element dd^32 lives in lane tx^8, same [i][j] slot
    const int dd0 = 4*tx;
    #pragma unroll
    for (int i = 0; i < 4; ++i) {
        int row = by*64 + 4*ty + i;
        int b = row >> 11, s = row & (S_ - 1);
        fvec4 v;
        #pragma unroll
        for (int j = 0; j < 4; ++j) {
            int dd = dd0 + j;
            float partner = __shfl_xor(acc[i][j], 8, 64);
            float c  = cost[s*32 + (dd & 31)];
            float sn = sint[s*32 + (dd & 31)];
            v[j] = (dd < 32) ? fmaf(acc[i][j], c, -partner*sn)
                             : fmaf(acc[i][j], c,  partner*sn);
        }
        size_t base;
        if (mode == 1) {
            int hp = (bx & 3)*4 + (bx >> 2);   // swapaxes(2,3) head permute
            base = (((size_t)b*H_ + hp)*S_ + s)*HD_ + dd0;
        } else {
            base = (((size_t)b*G_ + bx)*S_ + s)*HD_ + dd0;
        }
        *(fvec4*)&outp[base] = v;
    }
}

// ---------------- flash attention (no mask), fp32, 64 q-rows per block ------
__global__ __launch_bounds__(256)
void flash_attn(const float* __restrict__ qr, const float* __restrict__ kr,
                const float* __restrict__ vr, float* __restrict__ attn)
{
    __shared__ float Qs[64][68];   // [row][d], Q pre-scaled by 1/8 (exact)
    __shared__ float Ks[64][68];   // [d][key] (transposed)
    __shared__ float Vs[64][68];   // [key][d]
    __shared__ float Ps[64][68];   // [row][key]
    const int nqt = S_/64;
    const int qt = blockIdx.x % nqt;
    const int h  = (blockIdx.x / nqt) % H_;
    const int b  = blockIdx.x / (nqt*H_);
    const int g  = h >> 2;                    // jnp.repeat: head h -> group h/4
    const float* Qp = qr + (((size_t)b*H_ + h)*S_ + (size_t)qt*64)*HD_;
    const float* Kp = kr + ((size_t)b*G_ + g)*(size_t)S_*HD_;
    const float* Vp = vr + ((size_t)b*G_ + g)*(size_t)S_*HD_;
    const int t = threadIdx.x;
    const int tx = t & 15, ty = t >> 4;

    {
        const int row = t >> 2, dc = (t & 3)*16;
        const float* src = Qp + (size_t)row*HD_ + dc;
        #pragma unroll
        for (int u = 0; u < 4; ++u) {
            fvec4 v = *(const fvec4*)(src + 4*u);
            *(fvec4*)&Qs[row][dc + 4*u] = v * 0.125f;
        }
    }

    float m[4], l[4], o[4][4];
    #pragma unroll
    for (int i = 0; i < 4; ++i) {
        m[i] = -INFINITY; l[i] = 0.f;
        #pragma unroll
        for (int j = 0; j < 4; ++j) o[i][j] = 0.f;
    }

    for (int kt = 0; kt < S_/64; ++kt) {
        __syncthreads();                       // prev PV done before overwrite
        {
            const int key = t >> 2, dc = (t & 3)*16;
            const float* ksrc = Kp + ((size_t)(kt*64 + key))*HD_ + dc;
            const float* vsrc = Vp + ((size_t)(kt*64 + key))*HD_ + dc;
            #pragma unroll
            for (int u = 0; u < 4; ++u) {
                fvec4 kv = *(const fvec4*)(ksrc + 4*u);
                Ks[dc+4*u+0][key] = kv[0];
                Ks[dc+4*u+1][key] = kv[1];
                Ks[dc+4*u+2][key] = kv[2];
                Ks[dc+4*u+3][key] = kv[3];
                *(fvec4*)&Vs[key][dc + 4*u] = *(const fvec4*)(vsrc + 4*u);
            }
        }
        __syncthreads();

        float sc[4][4] = {};
        #pragma unroll
        for (int dc = 0; dc < 16; ++dc) {
            fvec4 qq[4], kb[4];
            #pragma unroll
            for (int i = 0; i < 4; ++i) qq[i] = *(const fvec4*)&Qs[4*ty+i][4*dc];
            #pragma unroll
            for (int e = 0; e < 4; ++e) kb[e] = *(const fvec4*)&Ks[4*dc+e][4*tx];
            #pragma unroll
            for (int i = 0; i < 4; ++i)
                #pragma unroll
                for (int j = 0; j < 4; ++j) {
                    sc[i][j] = fmaf(qq[i][0], kb[0][j], sc[i][j]);
                    sc[i][j] = fmaf(qq[i][1], kb[1][j], sc[i][j]);
                    sc[i][j] = fmaf(qq[i][2], kb[2][j], sc[i][j]);
                    sc[i][j] = fmaf(qq[i][3], kb[3][j], sc[i][j]);
                }
        }

        // online softmax; rows 4ty+i, reduce across tx = lane bits 0..3
        #pragma unroll
        for (int i = 0; i < 4; ++i) {
            float rmax = fmaxf(fmaxf(sc[i][0], sc[i][1]), fmaxf(sc[i][2], sc[i][3]));
            rmax = fmaxf(rmax, __shfl_xor(rmax, 1, 64));
            rmax = fmaxf(rmax, __shfl_xor(rmax, 2, 64));
            rmax = fmaxf(rmax, __shfl_xor(rmax, 4, 64));
            rmax = fmaxf(rmax, __shfl_xor(rmax, 8, 64));
            float mn = fmaxf(m[i], rmax);
            float alpha = expf(m[i] - mn);
            m[i] = mn;
            fvec4 p;
            float rs = 0.f;
            #pragma unroll
            for (int j = 0; j < 4; ++j) { p[j] = expf(sc[i][j] - mn); rs += p[j]; }
            rs += __shfl_xor(rs, 1, 64);
            rs += __shfl_xor(rs, 2, 64);
            rs += __shfl_xor(rs, 4, 64);
            rs += __shfl_xor(rs, 8, 64);
            l[i] = l[i]*alpha + rs;
            #pragma unroll
            for (int j = 0; j < 4; ++j) o[i][j] *= alpha;
            *(fvec4*)&Ps[4*ty+i][4*tx] = p;
        }
        __syncthreads();

        #pragma unroll
        for (int jc = 0; jc < 16; ++jc) {
            fvec4 pa[4], vb[4];
            #pragma unroll
            for (int i = 0; i < 4; ++i) pa[i] = *(const fvec4*)&Ps[4*ty+i][4*jc];
            #pragma unroll
            for (int u = 0; u < 4; ++u) vb[u] = *(const fvec4*)&Vs[4*jc+u][4*tx];
            #pragma unroll
            for (int i = 0; i < 4; ++i)
                #pragma unroll
                for (int j = 0; j < 4; ++j) {
                    o[i][j] = fmaf(pa[i][0], vb[0][j], o[i][j]);
                    o[i][j] = fmaf(pa[i][1], vb[1][j], o[i][j]);
                    o[i][j] = fmaf(pa[i][2], vb[2][j], o[i][j]);
                    o[i][j] = fmaf(pa[i][3], vb[3][j], o[i][j]);
                }
        }
    }

    #pragma unroll
    for (int i = 0; i < 4; ++i) {
        int s = qt*64 + 4*ty + i;
        float invl = 1.0f / l[i];
        fvec4 v;
        #pragma unroll
        for (int j = 0; j < 4; ++j) v[j] = o[i][j] * invl;
        *(fvec4*)&attn[((size_t)b*S_ + s)*D_ + h*HD_ + 4*tx] = v;
    }
}

extern "C" void kernel_launch(void* const* d_in, const int* in_sizes, int n_in,
                              void* d_out, int out_size, void* d_ws, size_t ws_size,
                              hipStream_t stream)
{
    const float* x  = (const float*)d_in[0];
    const float* Wq = (const float*)d_in[1];
    const float* Wk = (const float*)d_in[2];
    const float* Wv = (const float*)d_in[3];
    const float* Wo = (const float*)d_in[4];
    float* out = (float*)d_out;
    float* ws  = (float*)d_ws;

    // workspace layout (floats): total ~11.1M floats = 44.6 MB
    float* qr   = ws;                              // B*H*S*HD = 4194304
    float* kr   = qr   + (size_t)B_*H_*S_*HD_;     // B*G*S*HD = 1048576
    float* vr   = kr   + (size_t)B_*G_*S_*HD_;     // 1048576
    float* attn = vr   + (size_t)B_*G_*S_*HD_;     // B*S*D    = 4194304
    float* wkm  = attn + (size_t)B_*S_*D_;         // 262144
    float* wvm  = wkm  + (size_t)G_*HD_*D_;        // 262144
    float* cost = wvm  + (size_t)G_*HD_*D_;        // 65536
    float* sint = cost + (size_t)S_*32;            // 65536

    const int M = B_*S_;
    prep_kernel<<<(G_*HD_*D_ + 255)/256, 256, 0, stream>>>(Wk, Wv, wkm, wvm, cost, sint);
    gemm_nt<<<(M/64)*(D_/64),      256, 0, stream>>>(x,    Wq,  qr,  D_,      D_, 1, cost, sint);
    gemm_nt<<<(M/64)*((G_*HD_)/64),256, 0, stream>>>(x,    wkm, kr,  G_*HD_,  D_, 2, cost, sint);
    gemm_nt<<<(M/64)*((G_*HD_)/64),256, 0, stream>>>(x,    wvm, vr,  G_*HD_,  D_, 3, cost, sint);
    flash_attn<<<B_*H_*(S_/64),    256, 0, stream>>>(qr, kr, vr, attn);
    gemm_nt<<<(M/64)*(D_/64),      256, 0, stream>>>(attn, Wo,  out, D_,      D_, 0, cost, sint);
}

// Round 2
// 488.273 us; speedup vs baseline: 2.3804x; 2.3804x over previous
//
#include <hip/hip_runtime.h>
#include <hip/hip_bf16.h>
#include <math.h>

#define B_ 2
#define S_ 2048
#define D_ 1024
#define H_ 16
#define G_ 4
#define HPG_ 4
#define HD_ 64

typedef float fvec4 __attribute__((ext_vector_type(4)));
typedef float f32x4 __attribute__((ext_vector_type(4)));
typedef short s16x8 __attribute__((ext_vector_type(8)));
typedef unsigned short u16x4 __attribute__((ext_vector_type(4)));

__device__ __forceinline__ unsigned short f2b(float f) {
    __hip_bfloat16 h = __float2bfloat16(f);
    return __builtin_bit_cast(unsigned short, h);
}

#define MFMA16(a, b, c) __builtin_amdgcn_mfma_f32_16x16x32_bf16(a, b, c, 0, 0, 0)

#define GLOAD16(gp, lp) __builtin_amdgcn_global_load_lds(                      \
    (const __attribute__((address_space(1))) void*)(gp),                      \
    (__attribute__((address_space(3))) void*)(lp), 16, 0, 0)

// ---------------- prep: pooled K/V weights + rope tables ----------------
__global__ __launch_bounds__(256)
void prep_kernel(const float* __restrict__ Wk, const float* __restrict__ Wv,
                 float* __restrict__ wkm, float* __restrict__ wvm,
                 float* __restrict__ cost, float* __restrict__ sint)
{
    int idx = blockIdx.x * 256 + threadIdx.x;
    if (idx < G_*HD_*D_) {
        int c  = idx & (D_ - 1);
        int rd = idx >> 10;
        int g  = rd >> 6, d = rd & 63;
        float sk = 0.f, sv = 0.f;
        #pragma unroll
        for (int p = 0; p < HPG_; ++p) {
            int row = (g*HPG_ + p)*HD_ + d;
            sk += Wk[(size_t)row*D_ + c];
            sv += Wv[(size_t)row*D_ + c];
        }
        wkm[idx] = sk * 0.25f;
        wvm[idx] = sv * 0.25f;
    }
    if (idx < S_*32) {
        int s = idx >> 5, f = idx & 31;
        float inv = 1.0f / powf(10000.0f, (float)f * (1.0f/32.0f));
        float fr  = (float)s * inv;
        cost[idx] = cosf(fr);
        sint[idx] = sinf(fr);
    }
}

// ---------------- NT GEMM: C = A(MxK) * B(NxK)^T, 64x64 tile, 4x4 micro ----
// mode 0: fp32 plain -> outf[row*N + col]                  (O-projection)
// mode 1: bf16 rope + head permute -> qr[b][h'][s][dd]     (Q projection)
// mode 2: bf16 rope -> kr[b][g][s][dd]                     (K projection)
// mode 3: bf16 TRANSPOSED -> vt[b][g][dd][s]               (V projection)
__global__ __launch_bounds__(256)
void gemm_nt(const float* __restrict__ A, const float* __restrict__ Bm,
             float* __restrict__ outf, unsigned short* __restrict__ outb,
             int N, int K, int mode,
             const float* __restrict__ cost, const float* __restrict__ sint)
{
    __shared__ float As[16][68];
    __shared__ float Bs[16][68];
    const int nb = N >> 6;
    const int bx = blockIdx.x % nb;
    const int by = blockIdx.x / nb;
    const int t  = threadIdx.x;
    const int tx = t & 15, ty = t >> 4;
    const float* Ab = A  + (size_t)by*64*K;
    const float* Bb = Bm + (size_t)bx*64*K;
    float acc[4][4] = {};
    for (int k0 = 0; k0 < K; k0 += 16) {
        __syncthreads();
        #pragma unroll
        for (int i = 0; i < 4; ++i) {
            As[tx][ty + 16*i] = Ab[(size_t)(ty + 16*i)*K + k0 + tx];
            Bs[tx][ty + 16*i] = Bb[(size_t)(ty + 16*i)*K + k0 + tx];
        }
        __syncthreads();
        #pragma unroll
        for (int k = 0; k < 16; ++k) {
            fvec4 a = *(const fvec4*)&As[k][4*ty];
            fvec4 b = *(const fvec4*)&Bs[k][4*tx];
            #pragma unroll
            for (int i = 0; i < 4; ++i)
                #pragma unroll
                for (int j = 0; j < 4; ++j)
                    acc[i][j] = fmaf(a[i], b[j], acc[i][j]);
        }
    }

    if (mode == 0) {
        #pragma unroll
        for (int i = 0; i < 4; ++i) {
            int row = by*64 + 4*ty + i;
            fvec4 v;
            #pragma unroll
            for (int j = 0; j < 4; ++j) v[j] = acc[i][j];
            *(fvec4*)&outf[(size_t)row*N + bx*64 + 4*tx] = v;
        }
        return;
    }
    if (mode == 3) {
        int row0 = by*64 + 4*ty;
        int b = row0 >> 11, s0 = row0 & (S_ - 1);
        #pragma unroll
        for (int j = 0; j < 4; ++j) {
            u16x4 v;
            #pragma unroll
            for (int i = 0; i < 4; ++i) v[i] = f2b(acc[i][j]);
            int d = 4*tx + j;
            *(u16x4*)&outb[(((size_t)b*G_ + bx)*HD_ + d)*S_ + s0] = v;
        }
        return;
    }
    // rope modes: partner element dd^32 lives in lane tx^8, same [i][j] slot
    const int dd0 = 4*tx;
    #pragma unroll
    for (int i = 0; i < 4; ++i) {
        int row = by*64 + 4*ty + i;
        int b = row >> 11, s = row & (S_ - 1);
        u16x4 v;
        #pragma unroll
        for (int j = 0; j < 4; ++j) {
            int dd = dd0 + j;
            float partner = __shfl_xor(acc[i][j], 8, 64);
            float c  = cost[s*32 + (dd & 31)];
            float sn = sint[s*32 + (dd & 31)];
            float rv = (dd < 32) ? fmaf(acc[i][j], c, -partner*sn)
                                 : fmaf(acc[i][j], c,  partner*sn);
            v[j] = f2b(rv);
        }
        size_t base;
        if (mode == 1) {
            int hp = (bx & 3)*4 + (bx >> 2);   // swapaxes(2,3) head permute
            base = (((size_t)b*H_ + hp)*S_ + s)*HD_ + dd0;
        } else {
            base = (((size_t)b*G_ + bx)*S_ + s)*HD_ + dd0;
        }
        *(u16x4*)&outb[base] = v;
    }
}

// ---------------- MFMA flash attention -------------------------------------
// 4 waves x 32 q-rows (QBLK=128), KVBLK=64, D=64. K staged [key][d] swizzled,
// V staged from pre-transposed vt as [d][key] swizzled, both via
// global_load_lds w/ pre-swizzled global source. P via swizzled LDS.
__device__ __forceinline__ void stage_tile(const unsigned short* Kp, const unsigned short* Vp,
                                           unsigned short* ksbuf, unsigned short* vsbuf,
                                           int kt, int w, int l)
{
    const int srow = l >> 3;            // 0..7
    const int schk = (l & 7) ^ srow;    // swizzled 8-elem chunk
    #pragma unroll
    for (int i = 0; i < 2; ++i) {
        const int row = 16*w + 8*i + srow;          // row & 7 == srow
        const unsigned short* gk = Kp + ((size_t)(kt*64 + row))*HD_ + 8*schk;
        const unsigned short* gv = Vp + (size_t)row*S_ + kt*64 + 8*schk;
        GLOAD16(gk, ksbuf + (16*w + 8*i)*64);
        GLOAD16(gv, vsbuf + (16*w + 8*i)*64);
    }
}

__global__ __launch_bounds__(256)
void flash_attn_mfma(const unsigned short* __restrict__ qr,
                     const unsigned short* __restrict__ kr,
                     const unsigned short* __restrict__ vt,
                     float* __restrict__ attn)
{
    __shared__ unsigned short Ks[2][64*64];
    __shared__ unsigned short Vs[2][64*64];
    __shared__ unsigned short Ps[4][32*64];

    const int nqt = S_/128;
    const int qt = blockIdx.x % nqt;
    const int h  = (blockIdx.x/nqt) % H_;
    const int b  = blockIdx.x/(nqt*H_);
    const int g  = h >> 2;
    const int t  = threadIdx.x;
    const int w  = t >> 6;
    const int l  = t & 63;
    const int lg = l >> 4;
    const int lr = l & 15;

    const unsigned short* Qp = qr + (((size_t)b*H_ + h)*S_ + (size_t)qt*128 + w*32)*HD_;
    const unsigned short* Kp = kr + ((size_t)b*G_ + g)*(size_t)S_*HD_;
    const unsigned short* Vp = vt + ((size_t)b*G_ + g)*(size_t)HD_*S_;

    // Q fragments: A-layout row = lr (+16*rt), k(=d) = 8*lg+j (+32*kh)
    s16x8 qf[2][2];
    #pragma unroll
    for (int rt = 0; rt < 2; ++rt)
        #pragma unroll
        for (int kh = 0; kh < 2; ++kh)
            qf[rt][kh] = *(const s16x8*)(Qp + (size_t)(16*rt + lr)*HD_ + 32*kh + 8*lg);

    f32x4 o[2][4];
    float m[2][4], ld[2][4];
    #pragma unroll
    for (int rt = 0; rt < 2; ++rt)
        #pragma unroll
        for (int r = 0; r < 4; ++r) {
            m[rt][r] = -INFINITY; ld[rt][r] = 0.f;
        }
    #pragma unroll
    for (int rt = 0; rt < 2; ++rt)
        #pragma unroll
        for (int dt = 0; dt < 4; ++dt) o[rt][dt] = (f32x4){0.f,0.f,0.f,0.f};

    const float C   = 0.18033688011112044f;   // (1/8) * log2(e)
    const float THR = 44.0f;                  // defer-max threshold (raw score units)
    const int   NT  = S_/64;

    stage_tile(Kp, Vp, Ks[0], Vs[0], 0, w, l);

    for (int kt = 0; kt < NT; ++kt) {
        const int cur = kt & 1;
        if (kt + 1 < NT) {
            stage_tile(Kp, Vp, Ks[cur^1], Vs[cur^1], kt + 1, w, l);
            asm volatile("s_waitcnt vmcnt(4)" ::: "memory");
        } else {
            asm volatile("s_waitcnt vmcnt(0)" ::: "memory");
        }
        __builtin_amdgcn_s_barrier();

        // ---- QK^T: S[q][key] over d=64 (2 K-halves), 4 key tiles ----
        f32x4 sc[2][4] = {};
        #pragma unroll
        for (int ct = 0; ct < 4; ++ct) {
            const int key = 16*ct + lr;
            #pragma unroll
            for (int kh = 0; kh < 2; ++kh) {
                s16x8 kf = *(const s16x8*)&Ks[cur][key*64 + 8*((4*kh + lg) ^ (key & 7))];
                sc[0][ct] = MFMA16(qf[0][kh], kf, sc[0][ct]);
                sc[1][ct] = MFMA16(qf[1][kh], kf, sc[1][ct]);
            }
        }

        // ---- online softmax (rows = 16*rt + 4*lg + r, keys across ct,lr) ----
        float rmax[2][4];
        bool need = false;
        #pragma unroll
        for (int rt = 0; rt < 2; ++rt)
            #pragma unroll
            for (int r = 0; r < 4; ++r) {
                float v = fmaxf(fmaxf(sc[rt][0][r], sc[rt][1][r]),
                                fmaxf(sc[rt][2][r], sc[rt][3][r]));
                v = fmaxf(v, __shfl_xor(v, 1, 64));
                v = fmaxf(v, __shfl_xor(v, 2, 64));
                v = fmaxf(v, __shfl_xor(v, 4, 64));
                v = fmaxf(v, __shfl_xor(v, 8, 64));
                rmax[rt][r] = v;
                need = need || (v > m[rt][r] + THR);
            }
        if (__any(need ? 1 : 0)) {
            #pragma unroll
            for (int rt = 0; rt < 2; ++rt)
                #pragma unroll
                for (int r = 0; r < 4; ++r) {
                    float mn = fmaxf(m[rt][r], rmax[rt][r]);
                    float al = exp2f((m[rt][r] - mn) * C);
                    m[rt][r] = mn;
                    ld[rt][r] *= al;
                    #pragma unroll
                    for (int dt = 0; dt < 4; ++dt) o[rt][dt][r] *= al;
                }
        }
        #pragma unroll
        for (int rt = 0; rt < 2; ++rt) {
            float rs[4] = {0.f, 0.f, 0.f, 0.f};
            #pragma unroll
            for (int ct = 0; ct < 4; ++ct) {
                const int key = 16*ct + lr;
                #pragma unroll
                for (int r = 0; r < 4; ++r) {
                    float p = exp2f((sc[rt][ct][r] - m[rt][r]) * C);
                    rs[r] += p;
                    const int qrow = 16*rt + 4*lg + r;
                    Ps[w][qrow*64 + (key ^ ((qrow & 7) << 3))] = f2b(p);
                }
            }
            #pragma unroll
            for (int r = 0; r < 4; ++r) {
                float v = rs[r];
                v += __shfl_xor(v, 1, 64);
                v += __shfl_xor(v, 2, 64);
                v += __shfl_xor(v, 4, 64);
                v += __shfl_xor(v, 8, 64);
                ld[rt][r] += v;
            }
        }

        // ---- PV: O += P[q][key] * V[key][d] (2 key-slices of 32) ----
        #pragma unroll
        for (int ks = 0; ks < 2; ++ks) {
            s16x8 pf[2];
            #pragma unroll
            for (int rt = 0; rt < 2; ++rt)
                pf[rt] = *(const s16x8*)&Ps[w][(16*rt + lr)*64 + 8*((4*ks + lg) ^ (lr & 7))];
            #pragma unroll
            for (int dt = 0; dt < 4; ++dt) {
                const int d = 16*dt + lr;
                s16x8 vf = *(const s16x8*)&Vs[cur][d*64 + 8*((4*ks + lg) ^ (d & 7))];
                o[0][dt] = MFMA16(pf[0], vf, o[0][dt]);
                o[1][dt] = MFMA16(pf[1], vf, o[1][dt]);
            }
        }
        asm volatile("" ::: "memory");   // keep Vs/Ks reads above the barrier
        __builtin_amdgcn_s_barrier();
    }

    #pragma unroll
    for (int rt = 0; rt < 2; ++rt)
        #pragma unroll
        for (int r = 0; r < 4; ++r) {
            const float inv = 1.0f / ld[rt][r];
            const int s = qt*128 + w*32 + 16*rt + 4*lg + r;
            #pragma unroll
            for (int dt = 0; dt < 4; ++dt)
                attn[((size_t)b*S_ + s)*D_ + h*HD_ + 16*dt + lr] = o[rt][dt][r] * inv;
        }
}

extern "C" void kernel_launch(void* const* d_in, const int* in_sizes, int n_in,
                              void* d_out, int out_size, void* d_ws, size_t ws_size,
                              hipStream_t stream)
{
    const float* x  = (const float*)d_in[0];
    const float* Wq = (const float*)d_in[1];
    const float* Wk = (const float*)d_in[2];
    const float* Wv = (const float*)d_in[3];
    const float* Wo = (const float*)d_in[4];
    float* out = (float*)d_out;

    char* p = (char*)d_ws;
    unsigned short* qr = (unsigned short*)p; p += (size_t)B_*H_*S_*HD_*2;   // 8 MB
    unsigned short* kr = (unsigned short*)p; p += (size_t)B_*G_*S_*HD_*2;   // 2 MB
    unsigned short* vt = (unsigned short*)p; p += (size_t)B_*G_*HD_*S_*2;   // 2 MB
    float* attn = (float*)p; p += (size_t)B_*S_*D_*4;                       // 16 MB
    float* wkm  = (float*)p; p += (size_t)G_*HD_*D_*4;
    float* wvm  = (float*)p; p += (size_t)G_*HD_*D_*4;
    float* cost = (float*)p; p += (size_t)S_*32*4;
    float* sint = (float*)p;

    const int M = B_*S_;
    prep_kernel<<<(G_*HD_*D_ + 255)/256, 256, 0, stream>>>(Wk, Wv, wkm, wvm, cost, sint);
    gemm_nt<<<(M/64)*(D_/64),       256, 0, stream>>>(x,    Wq,  nullptr, qr, D_,     D_, 1, cost, sint);
    gemm_nt<<<(M/64)*((G_*HD_)/64), 256, 0, stream>>>(x,    wkm, nullptr, kr, G_*HD_, D_, 2, cost, sint);
    gemm_nt<<<(M/64)*((G_*HD_)/64), 256, 0, stream>>>(x,    wvm, nullptr, vt, G_*HD_, D_, 3, cost, sint);
    flash_attn_mfma<<<B_*H_*(S_/128), 256, 0, stream>>>(qr, kr, vt, attn);
    gemm_nt<<<(M/64)*(D_/64),       256, 0, stream>>>(attn, Wo,  out, nullptr, D_,    D_, 0, cost, sint);
}

// Round 3
// 170.051 us; speedup vs baseline: 6.8351x; 2.8713x over previous
//
#include <hip/hip_runtime.h>
#include <hip/hip_bf16.h>
#include <math.h>

#define B_ 2
#define S_ 2048
#define D_ 1024
#define H_ 16
#define G_ 4
#define HD_ 64

typedef float f32x4 __attribute__((ext_vector_type(4)));
typedef short s16x8 __attribute__((ext_vector_type(8)));
typedef unsigned short u16x4 __attribute__((ext_vector_type(4)));

__device__ __forceinline__ unsigned short f2b(float f) {
    __hip_bfloat16 h = __float2bfloat16(f);
    return __builtin_bit_cast(unsigned short, h);
}

#define MFMA16(a, b, c) __builtin_amdgcn_mfma_f32_16x16x32_bf16(a, b, c, 0, 0, 0)

#define GLOAD16(gp, lp) __builtin_amdgcn_global_load_lds(                      \
    (const __attribute__((address_space(1))) void*)(gp),                      \
    (__attribute__((address_space(3))) void*)(lp), 16, 0, 0)

// ---------------- prep: bf16 casts + pooled K/V weights + rope tables -------
// wb rows: [0,1024) = Wq ; [1024,1280) = mean_p Wk ; [1280,1536) = mean_p Wv
__global__ __launch_bounds__(256)
void prep_all(const float* __restrict__ x,  const float* __restrict__ Wq,
              const float* __restrict__ Wk, const float* __restrict__ Wv,
              const float* __restrict__ Wo,
              unsigned short* __restrict__ xb, unsigned short* __restrict__ wb,
              unsigned short* __restrict__ wob,
              float* __restrict__ cost, float* __restrict__ sint)
{
    const int NQ_WB = (1536*1024)/4;
    const int NQ_WO = (1024*1024)/4;
    const int NQ_X  = (B_*S_*D_)/4;
    int q = blockIdx.x*256 + threadIdx.x;
    if (q < NQ_WB) {
        const int idx = q*4, row = idx >> 10, c = idx & 1023;
        u16x4 o;
        if (row < 1024) {
            f32x4 v = *(const f32x4*)&Wq[(size_t)row*1024 + c];
            #pragma unroll
            for (int j = 0; j < 4; ++j) o[j] = f2b(v[j]);
        } else {
            const int rd = row - 1024, kv = rd >> 8, gd = rd & 255;
            const int g = gd >> 6, d = gd & 63;
            const float* W = kv ? Wv : Wk;
            f32x4 sum = {0.f, 0.f, 0.f, 0.f};
            #pragma unroll
            for (int p = 0; p < 4; ++p)
                sum += *(const f32x4*)&W[(size_t)((g*4 + p)*64 + d)*1024 + c];
            #pragma unroll
            for (int j = 0; j < 4; ++j) o[j] = f2b(sum[j]*0.25f);
        }
        *(u16x4*)&wb[idx] = o;
        return;
    }
    q -= NQ_WB;
    if (q < NQ_WO) {
        const int idx = q*4;
        f32x4 v = *(const f32x4*)&Wo[idx];
        u16x4 o;
        #pragma unroll
        for (int j = 0; j < 4; ++j) o[j] = f2b(v[j]);
        *(u16x4*)&wob[idx] = o;
        return;
    }
    q -= NQ_WO;
    if (q < NQ_X) {
        const int idx = q*4;
        f32x4 v = *(const f32x4*)&x[idx];
        u16x4 o;
        #pragma unroll
        for (int j = 0; j < 4; ++j) o[j] = f2b(v[j]);
        *(u16x4*)&xb[idx] = o;
        return;
    }
    q -= NQ_X;
    if (q < (S_*32)/4) {
        const int idx = q*4, s = idx >> 5, f0 = idx & 31;
        #pragma unroll
        for (int j = 0; j < 4; ++j) {
            const float f = (float)(f0 + j);
            const float fr = (float)s * powf(10000.0f, -f*(1.0f/32.0f));
            cost[idx + j] = cosf(fr);
            sint[idx + j] = sinf(fr);
        }
    }
}

// ---------------- MFMA GEMM: C = A(Mx1024) * B(Nx1024)^T, 128x128 tile ------
// 4 waves, each owns a 64x64 quadrant (4x4 frags of 16x16x32), BK=64, dbuf LDS,
// global_load_lds w/ pre-swizzled source, counted vmcnt, XCD-chunked swizzle.
// MODE 0: fused QKV epilogue (bx<8: Q rope+permute; bx<10: K rope; else V^T)
// MODE 1: fp32 store (O-projection)
template<int MODE>
__global__ __launch_bounds__(256)
void gemm_mfma(const unsigned short* __restrict__ Am,
               const unsigned short* __restrict__ Bm,
               unsigned short* __restrict__ qr,
               unsigned short* __restrict__ kr,
               unsigned short* __restrict__ vt,
               float* __restrict__ outf,
               const float* __restrict__ cost,
               const float* __restrict__ sint,
               int nbx)
{
    __shared__ unsigned short As[2][128*64];
    __shared__ unsigned short Bs[2][128*64];

    const int nwg = gridDim.x;
    const int cpx = nwg >> 3;                       // grid % 8 == 0 always here
    const int bid = blockIdx.x;
    const int swz = (bid & 7)*cpx + (bid >> 3);     // XCD-chunked (bijective)
    const int bx = swz % nbx, by = swz / nbx;

    const int t  = threadIdx.x;
    const int w  = t >> 6, l = t & 63;
    const int lg = l >> 4, lr = l & 15;
    const int wr = w >> 1, wc = w & 1;

    const unsigned short* gA = Am + (size_t)by*128*D_;
    const unsigned short* gB = Bm + (size_t)bx*128*D_;

    const int srow = l >> 3;            // 0..7
    const int schk = (l & 7) ^ srow;    // pre-swizzled 16B chunk in 128B row

#define STAGE(buf, k0)                                                         \
    _Pragma("unroll")                                                          \
    for (int i_ = 0; i_ < 4; ++i_) {                                           \
        const int row_ = 32*w + 8*i_ + srow;                                   \
        GLOAD16(gA + (size_t)row_*D_ + (k0) + 8*schk, &As[buf][(32*w + 8*i_)*64]); \
        GLOAD16(gB + (size_t)row_*D_ + (k0) + 8*schk, &Bs[buf][(32*w + 8*i_)*64]); \
    }

    f32x4 acc[4][4] = {};

    STAGE(0, 0);
    #pragma unroll 1
    for (int kt = 0; kt < 16; ++kt) {
        const int cur = kt & 1;
        if (kt < 15) {
            STAGE(cur ^ 1, 64*(kt + 1));
            asm volatile("s_waitcnt vmcnt(8)" ::: "memory");
        } else {
            asm volatile("s_waitcnt vmcnt(0)" ::: "memory");
        }
        __builtin_amdgcn_s_barrier();

        #pragma unroll
        for (int kk = 0; kk < 2; ++kk) {
            s16x8 af[4], bfr[4];
            #pragma unroll
            for (int m = 0; m < 4; ++m) {
                const int row = 64*wr + 16*m + lr;
                af[m] = *(const s16x8*)&As[cur][row*64 + 8*((lg + 4*kk) ^ (row & 7))];
            }
            #pragma unroll
            for (int n = 0; n < 4; ++n) {
                const int col = 64*wc + 16*n + lr;
                bfr[n] = *(const s16x8*)&Bs[cur][col*64 + 8*((lg + 4*kk) ^ (col & 7))];
            }
            #pragma unroll
            for (int m = 0; m < 4; ++m)
                #pragma unroll
                for (int n = 0; n < 4; ++n)
                    acc[m][n] = MFMA16(af[m], bfr[n], acc[m][n]);
        }
        asm volatile("s_waitcnt lgkmcnt(0)" ::: "memory");
        __builtin_amdgcn_s_barrier();
    }
#undef STAGE

    if (MODE == 1) {
        #pragma unroll
        for (int m = 0; m < 4; ++m)
            #pragma unroll
            for (int r = 0; r < 4; ++r) {
                const int row = by*128 + 64*wr + 16*m + 4*lg + r;
                #pragma unroll
                for (int n = 0; n < 4; ++n)
                    outf[(size_t)row*D_ + bx*128 + 64*wc + 16*n + lr] = acc[m][n][r];
            }
        return;
    }

    if (bx < 10) {   // Q (bx<8) or K (bx 8,9): rope; partner dd^32 = acc[m][n^2]
        #pragma unroll
        for (int m = 0; m < 4; ++m) {
            #pragma unroll
            for (int r = 0; r < 4; ++r) {
                const int row = by*128 + 64*wr + 16*m + 4*lg + r;
                const int b = row >> 11, s = row & (S_ - 1);
                const float c_lo = cost[s*32 + lr],      s_lo = sint[s*32 + lr];
                const float c_hi = cost[s*32 + 16 + lr], s_hi = sint[s*32 + 16 + lr];
                unsigned short vals[4];
                #pragma unroll
                for (int n = 0; n < 4; ++n) {
                    const float cc = (n & 1) ? c_hi : c_lo;
                    const float sn = (n & 1) ? s_hi : s_lo;
                    const float self = acc[m][n][r], part = acc[m][n ^ 2][r];
                    const float rv = (n < 2) ? fmaf(self, cc, -part*sn)
                                             : fmaf(self, cc,  part*sn);
                    vals[n] = f2b(rv);
                }
                size_t base;
                unsigned short* dst;
                if (bx < 8) {
                    const int hh = 2*bx + wc;
                    const int hp = (hh & 3)*4 + (hh >> 2);  // swapaxes(2,3)
                    base = (((size_t)b*H_ + hp)*S_ + s)*HD_;
                    dst = qr;
                } else {
                    const int g = (bx - 8)*2 + wc;
                    base = (((size_t)b*G_ + g)*S_ + s)*HD_;
                    dst = kr;
                }
                #pragma unroll
                for (int n = 0; n < 4; ++n) dst[base + 16*n + lr] = vals[n];
            }
        }
    } else {         // V: store transposed vt[b][g][dd][s], 4 consecutive s
        const int g = (bx - 10)*2 + wc;
        #pragma unroll
        for (int m = 0; m < 4; ++m) {
            const int row0 = by*128 + 64*wr + 16*m + 4*lg;
            const int b = row0 >> 11, s0 = row0 & (S_ - 1);
            #pragma unroll
            for (int n = 0; n < 4; ++n) {
                const int dd = 16*n + lr;
                u16x4 v;
                #pragma unroll
                for (int r = 0; r < 4; ++r) v[r] = f2b(acc[m][n][r]);
                *(u16x4*)&vt[(((size_t)b*G_ + g)*HD_ + dd)*S_ + s0] = v;
            }
        }
    }
}

// ---------------- MFMA flash attention (bf16 out) ----------------------------
__device__ __forceinline__ void stage_tile(const unsigned short* Kp, const unsigned short* Vp,
                                           unsigned short* ksbuf, unsigned short* vsbuf,
                                           int kt, int w, int l)
{
    const int srow = l >> 3;
    const int schk = (l & 7) ^ srow;
    #pragma unroll
    for (int i = 0; i < 2; ++i) {
        const int row = 16*w + 8*i + srow;
        const unsigned short* gk = Kp + ((size_t)(kt*64 + row))*HD_ + 8*schk;
        const unsigned short* gv = Vp + (size_t)row*S_ + kt*64 + 8*schk;
        GLOAD16(gk, ksbuf + (16*w + 8*i)*64);
        GLOAD16(gv, vsbuf + (16*w + 8*i)*64);
    }
}

__global__ __launch_bounds__(256)
void flash_attn_mfma(const unsigned short* __restrict__ qr,
                     const unsigned short* __restrict__ kr,
                     const unsigned short* __restrict__ vt,
                     unsigned short* __restrict__ attnb)
{
    __shared__ unsigned short Ks[2][64*64];
    __shared__ unsigned short Vs[2][64*64];
    __shared__ unsigned short Ps[4][32*64];

    const int nqt = S_/128;
    const int bid = blockIdx.x;
    const int cpx = gridDim.x >> 3;
    const int swz = (bid & 7)*cpx + (bid >> 3);     // XCD-chunked
    const int qt = swz % nqt;
    const int h  = (swz/nqt) % H_;
    const int b  = swz/(nqt*H_);
    const int g  = h >> 2;
    const int t  = threadIdx.x;
    const int w  = t >> 6;
    const int l  = t & 63;
    const int lg = l >> 4;
    const int lr = l & 15;

    const unsigned short* Qp = qr + (((size_t)b*H_ + h)*S_ + (size_t)qt*128 + w*32)*HD_;
    const unsigned short* Kp = kr + ((size_t)b*G_ + g)*(size_t)S_*HD_;
    const unsigned short* Vp = vt + ((size_t)b*G_ + g)*(size_t)HD_*S_;

    s16x8 qf[2][2];
    #pragma unroll
    for (int rt = 0; rt < 2; ++rt)
        #pragma unroll
        for (int kh = 0; kh < 2; ++kh)
            qf[rt][kh] = *(const s16x8*)(Qp + (size_t)(16*rt + lr)*HD_ + 32*kh + 8*lg);

    f32x4 o[2][4];
    float m[2][4], ld[2][4];
    #pragma unroll
    for (int rt = 0; rt < 2; ++rt)
        #pragma unroll
        for (int r = 0; r < 4; ++r) { m[rt][r] = -INFINITY; ld[rt][r] = 0.f; }
    #pragma unroll
    for (int rt = 0; rt < 2; ++rt)
        #pragma unroll
        for (int dt = 0; dt < 4; ++dt) o[rt][dt] = (f32x4){0.f,0.f,0.f,0.f};

    const float C   = 0.18033688011112044f;   // (1/8) * log2(e)
    const float THR = 44.0f;
    const int   NT  = S_/64;

    stage_tile(Kp, Vp, Ks[0], Vs[0], 0, w, l);

    for (int kt = 0; kt < NT; ++kt) {
        const int cur = kt & 1;
        if (kt + 1 < NT) {
            stage_tile(Kp, Vp, Ks[cur^1], Vs[cur^1], kt + 1, w, l);
            asm volatile("s_waitcnt vmcnt(4)" ::: "memory");
        } else {
            asm volatile("s_waitcnt vmcnt(0)" ::: "memory");
        }
        __builtin_amdgcn_s_barrier();

        f32x4 sc[2][4] = {};
        #pragma unroll
        for (int ct = 0; ct < 4; ++ct) {
            const int key = 16*ct + lr;
            #pragma unroll
            for (int kh = 0; kh < 2; ++kh) {
                s16x8 kf = *(const s16x8*)&Ks[cur][key*64 + 8*((4*kh + lg) ^ (key & 7))];
                sc[0][ct] = MFMA16(qf[0][kh], kf, sc[0][ct]);
                sc[1][ct] = MFMA16(qf[1][kh], kf, sc[1][ct]);
            }
        }

        float rmax[2][4];
        bool need = false;
        #pragma unroll
        for (int rt = 0; rt < 2; ++rt)
            #pragma unroll
            for (int r = 0; r < 4; ++r) {
                float v = fmaxf(fmaxf(sc[rt][0][r], sc[rt][1][r]),
                                fmaxf(sc[rt][2][r], sc[rt][3][r]));
                v = fmaxf(v, __shfl_xor(v, 1, 64));
                v = fmaxf(v, __shfl_xor(v, 2, 64));
                v = fmaxf(v, __shfl_xor(v, 4, 64));
                v = fmaxf(v, __shfl_xor(v, 8, 64));
                rmax[rt][r] = v;
                need = need || (v > m[rt][r] + THR);
            }
        if (__any(need ? 1 : 0)) {
            #pragma unroll
            for (int rt = 0; rt < 2; ++rt)
                #pragma unroll
                for (int r = 0; r < 4; ++r) {
                    float mn = fmaxf(m[rt][r], rmax[rt][r]);
                    float al = exp2f((m[rt][r] - mn) * C);
                    m[rt][r] = mn;
                    ld[rt][r] *= al;
                    #pragma unroll
                    for (int dt = 0; dt < 4; ++dt) o[rt][dt][r] *= al;
                }
        }
        #pragma unroll
        for (int rt = 0; rt < 2; ++rt) {
            float rs[4] = {0.f, 0.f, 0.f, 0.f};
            #pragma unroll
            for (int ct = 0; ct < 4; ++ct) {
                const int key = 16*ct + lr;
                #pragma unroll
                for (int r = 0; r < 4; ++r) {
                    float p = exp2f((sc[rt][ct][r] - m[rt][r]) * C);
                    rs[r] += p;
                    const int qrow = 16*rt + 4*lg + r;
                    Ps[w][qrow*64 + (key ^ ((qrow & 7) << 3))] = f2b(p);
                }
            }
            #pragma unroll
            for (int r = 0; r < 4; ++r) {
                float v = rs[r];
                v += __shfl_xor(v, 1, 64);
                v += __shfl_xor(v, 2, 64);
                v += __shfl_xor(v, 4, 64);
                v += __shfl_xor(v, 8, 64);
                ld[rt][r] += v;
            }
        }

        #pragma unroll
        for (int ks = 0; ks < 2; ++ks) {
            s16x8 pf[2];
            #pragma unroll
            for (int rt = 0; rt < 2; ++rt)
                pf[rt] = *(const s16x8*)&Ps[w][(16*rt + lr)*64 + 8*((4*ks + lg) ^ (lr & 7))];
            #pragma unroll
            for (int dt = 0; dt < 4; ++dt) {
                const int d = 16*dt + lr;
                s16x8 vf = *(const s16x8*)&Vs[cur][d*64 + 8*((4*ks + lg) ^ (d & 7))];
                o[0][dt] = MFMA16(pf[0], vf, o[0][dt]);
                o[1][dt] = MFMA16(pf[1], vf, o[1][dt]);
            }
        }
        asm volatile("s_waitcnt lgkmcnt(0)" ::: "memory");
        __builtin_amdgcn_s_barrier();
    }

    #pragma unroll
    for (int rt = 0; rt < 2; ++rt)
        #pragma unroll
        for (int r = 0; r < 4; ++r) {
            const float inv = 1.0f / ld[rt][r];
            const int s = qt*128 + w*32 + 16*rt + 4*lg + r;
            #pragma unroll
            for (int dt = 0; dt < 4; ++dt)
                attnb[((size_t)b*S_ + s)*D_ + h*HD_ + 16*dt + lr] = f2b(o[rt][dt][r]*inv);
        }
}

extern "C" void kernel_launch(void* const* d_in, const int* in_sizes, int n_in,
                              void* d_out, int out_size, void* d_ws, size_t ws_size,
                              hipStream_t stream)
{
    const float* x  = (const float*)d_in[0];
    const float* Wq = (const float*)d_in[1];
    const float* Wk = (const float*)d_in[2];
    const float* Wv = (const float*)d_in[3];
    const float* Wo = (const float*)d_in[4];
    float* out = (float*)d_out;

    char* p = (char*)d_ws;
    unsigned short* xb    = (unsigned short*)p; p += (size_t)B_*S_*D_*2;      // 8 MB
    unsigned short* wb    = (unsigned short*)p; p += (size_t)1536*1024*2;     // 3 MB
    unsigned short* wob   = (unsigned short*)p; p += (size_t)1024*1024*2;     // 2 MB
    unsigned short* qr    = (unsigned short*)p; p += (size_t)B_*H_*S_*HD_*2;  // 8 MB
    unsigned short* kr    = (unsigned short*)p; p += (size_t)B_*G_*S_*HD_*2;  // 2 MB
    unsigned short* vt    = (unsigned short*)p; p += (size_t)B_*G_*HD_*S_*2;  // 2 MB
    unsigned short* attnb = (unsigned short*)p; p += (size_t)B_*S_*D_*2;      // 8 MB
    float* cost = (float*)p; p += (size_t)S_*32*4;
    float* sint = (float*)p;

    prep_all<<<6720, 256, 0, stream>>>(x, Wq, Wk, Wv, Wo, xb, wb, wob, cost, sint);
    gemm_mfma<0><<<32*12, 256, 0, stream>>>(xb, wb, qr, kr, vt, nullptr, cost, sint, 12);
    flash_attn_mfma<<<B_*H_*(S_/128), 256, 0, stream>>>(qr, kr, vt, attnb);
    gemm_mfma<1><<<32*8, 256, 0, stream>>>(attnb, wob, nullptr, nullptr, nullptr, out, cost, sint, 8);
}

// Round 4
// 112.087 us; speedup vs baseline: 10.3697x; 1.5171x over previous
//
#include <hip/hip_runtime.h>
#include <hip/hip_bf16.h>
#include <math.h>

#define B_ 2
#define S_ 2048
#define D_ 1024
#define H_ 16
#define G_ 4
#define HD_ 64

typedef float f32x4  __attribute__((ext_vector_type(4)));
typedef float f32x16 __attribute__((ext_vector_type(16)));
typedef short s16x8  __attribute__((ext_vector_type(8)));
typedef unsigned short u16x4 __attribute__((ext_vector_type(4)));
typedef unsigned int   u32x4 __attribute__((ext_vector_type(4)));

__device__ __forceinline__ unsigned short f2b(float f) {
    __hip_bfloat16 h = __float2bfloat16(f);
    return __builtin_bit_cast(unsigned short, h);
}
__device__ __forceinline__ unsigned cvtpk(float lo, float hi) {
    unsigned r;
    asm("v_cvt_pk_bf16_f32 %0, %1, %2" : "=v"(r) : "v"(lo), "v"(hi));
    return r;
}
__device__ __forceinline__ void plswap(unsigned &a, unsigned &b) {
    asm("v_permlane32_swap_b32 %0, %1" : "+v"(a), "+v"(b));
}

#define MFMA16(a, b, c) __builtin_amdgcn_mfma_f32_16x16x32_bf16(a, b, c, 0, 0, 0)
#define MFMA32(a, b, c) __builtin_amdgcn_mfma_f32_32x32x16_bf16(a, b, c, 0, 0, 0)

#define GLOAD16(gp, lp) __builtin_amdgcn_global_load_lds(                      \
    (const __attribute__((address_space(1))) void*)(gp),                      \
    (__attribute__((address_space(3))) void*)(lp), 16, 0, 0)

// ---------------- prep: bf16 casts + pooled K/V weights + rope tables -------
__global__ __launch_bounds__(256)
void prep_all(const float* __restrict__ x,  const float* __restrict__ Wq,
              const float* __restrict__ Wk, const float* __restrict__ Wv,
              const float* __restrict__ Wo,
              unsigned short* __restrict__ xb, unsigned short* __restrict__ wb,
              unsigned short* __restrict__ wob,
              float* __restrict__ cost, float* __restrict__ sint)
{
    const int NQ_WB = (1536*1024)/4;
    const int NQ_WO = (1024*1024)/4;
    const int NQ_X  = (B_*S_*D_)/4;
    int q = blockIdx.x*256 + threadIdx.x;
    if (q < NQ_WB) {
        const int idx = q*4, row = idx >> 10, c = idx & 1023;
        u16x4 o;
        if (row < 1024) {
            f32x4 v = *(const f32x4*)&Wq[(size_t)row*1024 + c];
            #pragma unroll
            for (int j = 0; j < 4; ++j) o[j] = f2b(v[j]);
        } else {
            const int rd = row - 1024, kv = rd >> 8, gd = rd & 255;
            const int g = gd >> 6, d = gd & 63;
            const float* W = kv ? Wv : Wk;
            f32x4 sum = {0.f, 0.f, 0.f, 0.f};
            #pragma unroll
            for (int p = 0; p < 4; ++p)
                sum += *(const f32x4*)&W[(size_t)((g*4 + p)*64 + d)*1024 + c];
            #pragma unroll
            for (int j = 0; j < 4; ++j) o[j] = f2b(sum[j]*0.25f);
        }
        *(u16x4*)&wb[idx] = o;
        return;
    }
    q -= NQ_WB;
    if (q < NQ_WO) {
        const int idx = q*4;
        f32x4 v = *(const f32x4*)&Wo[idx];
        u16x4 o;
        #pragma unroll
        for (int j = 0; j < 4; ++j) o[j] = f2b(v[j]);
        *(u16x4*)&wob[idx] = o;
        return;
    }
    q -= NQ_WO;
    if (q < NQ_X) {
        const int idx = q*4;
        f32x4 v = *(const f32x4*)&x[idx];
        u16x4 o;
        #pragma unroll
        for (int j = 0; j < 4; ++j) o[j] = f2b(v[j]);
        *(u16x4*)&xb[idx] = o;
        return;
    }
    q -= NQ_X;
    if (q < (S_*32)/4) {
        const int idx = q*4, s = idx >> 5, f0 = idx & 31;
        #pragma unroll
        for (int j = 0; j < 4; ++j) {
            const float f = (float)(f0 + j);
            const float fr = (float)s * powf(10000.0f, -f*(1.0f/32.0f));
            cost[idx + j] = cosf(fr);
            sint[idx + j] = sinf(fr);
        }
    }
}

// ---------------- MFMA GEMM: C = A(Mx1024) * B(Nx1024)^T, 128x128 tile ------
// MODE 0: fused QKV epilogue (bx<8: Q rope+permute; bx<10: K rope; else V^T)
// MODE 1: fp32 store (O-projection)
template<int MODE>
__global__ __launch_bounds__(256)
void gemm_mfma(const unsigned short* __restrict__ Am,
               const unsigned short* __restrict__ Bm,
               unsigned short* __restrict__ qr,
               unsigned short* __restrict__ kr,
               unsigned short* __restrict__ vt,
               float* __restrict__ outf,
               const float* __restrict__ cost,
               const float* __restrict__ sint,
               int nbx)
{
    __shared__ unsigned short As[2][128*64];
    __shared__ unsigned short Bs[2][128*64];

    const int nwg = gridDim.x;
    const int cpx = nwg >> 3;
    const int bid = blockIdx.x;
    const int swz = (bid & 7)*cpx + (bid >> 3);     // XCD-chunked (bijective)
    const int bx = swz % nbx, by = swz / nbx;

    const int t  = threadIdx.x;
    const int w  = t >> 6, l = t & 63;
    const int lg = l >> 4, lr = l & 15;
    const int wr = w >> 1, wc = w & 1;

    const unsigned short* gA = Am + (size_t)by*128*D_;
    const unsigned short* gB = Bm + (size_t)bx*128*D_;

    const int srow = l >> 3;
    const int schk = (l & 7) ^ srow;

#define STAGE(buf, k0)                                                         \
    _Pragma("unroll")                                                          \
    for (int i_ = 0; i_ < 4; ++i_) {                                           \
        const int row_ = 32*w + 8*i_ + srow;                                   \
        GLOAD16(gA + (size_t)row_*D_ + (k0) + 8*schk, &As[buf][(32*w + 8*i_)*64]); \
        GLOAD16(gB + (size_t)row_*D_ + (k0) + 8*schk, &Bs[buf][(32*w + 8*i_)*64]); \
    }

    f32x4 acc[4][4] = {};

    STAGE(0, 0);
    #pragma unroll 1
    for (int kt = 0; kt < 16; ++kt) {
        const int cur = kt & 1;
        if (kt < 15) {
            STAGE(cur ^ 1, 64*(kt + 1));
            asm volatile("s_waitcnt vmcnt(8)" ::: "memory");
        } else {
            asm volatile("s_waitcnt vmcnt(0)" ::: "memory");
        }
        __builtin_amdgcn_s_barrier();

        #pragma unroll
        for (int kk = 0; kk < 2; ++kk) {
            s16x8 af[4], bfr[4];
            #pragma unroll
            for (int m = 0; m < 4; ++m) {
                const int row = 64*wr + 16*m + lr;
                af[m] = *(const s16x8*)&As[cur][row*64 + 8*((lg + 4*kk) ^ (row & 7))];
            }
            #pragma unroll
            for (int n = 0; n < 4; ++n) {
                const int col = 64*wc + 16*n + lr;
                bfr[n] = *(const s16x8*)&Bs[cur][col*64 + 8*((lg + 4*kk) ^ (col & 7))];
            }
            #pragma unroll
            for (int m = 0; m < 4; ++m)
                #pragma unroll
                for (int n = 0; n < 4; ++n)
                    acc[m][n] = MFMA16(af[m], bfr[n], acc[m][n]);
        }
        asm volatile("s_waitcnt lgkmcnt(0)" ::: "memory");
        __builtin_amdgcn_s_barrier();
    }
#undef STAGE

    if (MODE == 1) {
        #pragma unroll
        for (int m = 0; m < 4; ++m)
            #pragma unroll
            for (int r = 0; r < 4; ++r) {
                const int row = by*128 + 64*wr + 16*m + 4*lg + r;
                #pragma unroll
                for (int n = 0; n < 4; ++n)
                    outf[(size_t)row*D_ + bx*128 + 64*wc + 16*n + lr] = acc[m][n][r];
            }
        return;
    }

    if (bx < 10) {   // Q (bx<8) or K (bx 8,9): rope; partner dd^32 = acc[m][n^2]
        #pragma unroll
        for (int m = 0; m < 4; ++m) {
            #pragma unroll
            for (int r = 0; r < 4; ++r) {
                const int row = by*128 + 64*wr + 16*m + 4*lg + r;
                const int b = row >> 11, s = row & (S_ - 1);
                const float c_lo = cost[s*32 + lr],      s_lo = sint[s*32 + lr];
                const float c_hi = cost[s*32 + 16 + lr], s_hi = sint[s*32 + 16 + lr];
                unsigned short vals[4];
                #pragma unroll
                for (int n = 0; n < 4; ++n) {
                    const float cc = (n & 1) ? c_hi : c_lo;
                    const float sn = (n & 1) ? s_hi : s_lo;
                    const float self = acc[m][n][r], part = acc[m][n ^ 2][r];
                    const float rv = (n < 2) ? fmaf(self, cc, -part*sn)
                                             : fmaf(self, cc,  part*sn);
                    vals[n] = f2b(rv);
                }
                size_t base;
                unsigned short* dst;
                if (bx < 8) {
                    const int hh = 2*bx + wc;
                    const int hp = (hh & 3)*4 + (hh >> 2);  // swapaxes(2,3)
                    base = (((size_t)b*H_ + hp)*S_ + s)*HD_;
                    dst = qr;
                } else {
                    const int g = (bx - 8)*2 + wc;
                    base = (((size_t)b*G_ + g)*S_ + s)*HD_;
                    dst = kr;
                }
                #pragma unroll
                for (int n = 0; n < 4; ++n) dst[base + 16*n + lr] = vals[n];
            }
        }
    } else {         // V: store transposed vt[b][g][dd][s]
        const int g = (bx - 10)*2 + wc;
        #pragma unroll
        for (int m = 0; m < 4; ++m) {
            const int row0 = by*128 + 64*wr + 16*m + 4*lg;
            const int b = row0 >> 11, s0 = row0 & (S_ - 1);
            #pragma unroll
            for (int n = 0; n < 4; ++n) {
                const int dd = 16*n + lr;
                u16x4 v;
                #pragma unroll
                for (int r = 0; r < 4; ++r) v[r] = f2b(acc[m][n][r]);
                *(u16x4*)&vt[(((size_t)b*G_ + g)*HD_ + dd)*S_ + s0] = v;
            }
        }
    }
}

// ---------------- MFMA flash attention, in-register softmax -----------------
// 4 waves x 32 q-rows, 32x32x16 MFMA, swapped QK^T (S^T = K·Q^T) so each lane
// owns one q-row; P->bf16 via v_cvt_pk_bf16_f32; redistribution to PV
// A-operand via v_permlane32_swap_b32. Defer-max: m=0, rescale only if
// pmax > m+THR (never on N(0,1)-scale scores; exact rare path via LDS).
__device__ __forceinline__ void stage_tile(const unsigned short* Kp, const unsigned short* Vp,
                                           unsigned short* ksbuf, unsigned short* vsbuf,
                                           int kt, int w, int l)
{
    const int srow = l >> 3;
    const int schk = (l & 7) ^ srow;
    #pragma unroll
    for (int i = 0; i < 2; ++i) {
        const int row = 16*w + 8*i + srow;
        const unsigned short* gk = Kp + ((size_t)(kt*64 + row))*HD_ + 8*schk;
        const unsigned short* gv = Vp + (size_t)row*S_ + kt*64 + 8*schk;
        GLOAD16(gk, ksbuf + (16*w + 8*i)*64);
        GLOAD16(gv, vsbuf + (16*w + 8*i)*64);
    }
}

__global__ __launch_bounds__(256)
void flash_attn_mfma(const unsigned short* __restrict__ qr,
                     const unsigned short* __restrict__ kr,
                     const unsigned short* __restrict__ vt,
                     unsigned short* __restrict__ attnb)
{
    __shared__ unsigned short Ks[2][64*64];
    __shared__ unsigned short Vs[2][64*64];
    __shared__ float xbuf[4][32];              // per-wave transpose scratch

    const int nqt = S_/128;
    const int bid = blockIdx.x;
    const int cpx = gridDim.x >> 3;
    const int swz = (bid & 7)*cpx + (bid >> 3);
    const int qt = swz % nqt;
    const int h  = (swz/nqt) % H_;
    const int b  = swz/(nqt*H_);
    const int g  = h >> 2;
    const int t  = threadIdx.x;
    const int w  = t >> 6;
    const int l  = t & 63;
    const int hi = l >> 5;                     // lane half
    const int li = l & 31;                     // q-row owned by this lane

    const unsigned short* Qp = qr + (((size_t)b*H_ + h)*S_ + (size_t)qt*128 + w*32)*HD_;
    const unsigned short* Kp = kr + ((size_t)b*G_ + g)*(size_t)S_*HD_;
    const unsigned short* Vp = vt + ((size_t)b*G_ + g)*(size_t)HD_*S_;

    // Q as B-operand of mfma(K,Q): lane holds Q[q=li][d = 16*kk + 8*hi + j]
    s16x8 qf[4];
    #pragma unroll
    for (int kk = 0; kk < 4; ++kk)
        qf[kk] = *(const s16x8*)(Qp + (size_t)li*HD_ + 16*kk + 8*hi);

    f32x16 o[2];
    #pragma unroll
    for (int dt = 0; dt < 2; ++dt)
        #pragma unroll
        for (int e = 0; e < 16; ++e) o[dt][e] = 0.f;
    float m = 0.f, ld = 0.f;

    const float C   = 0.18033688011112044f;   // (1/8)*log2(e)
    const float THR = 32.0f;                  // raw-score defer threshold
    const int   NT  = S_/64;

    stage_tile(Kp, Vp, Ks[0], Vs[0], 0, w, l);

    #pragma unroll 1
    for (int kt = 0; kt < NT; ++kt) {
        const int cur = kt & 1;
        if (kt + 1 < NT) {
            stage_tile(Kp, Vp, Ks[cur^1], Vs[cur^1], kt + 1, w, l);
            asm volatile("s_waitcnt vmcnt(4)" ::: "memory");
        } else {
            asm volatile("s_waitcnt vmcnt(0)" ::: "memory");
        }
        __builtin_amdgcn_s_barrier();

        #pragma unroll
        for (int kt2 = 0; kt2 < 2; ++kt2) {
            // ---- QK^T: S^T[key][q], key tile = 32*kt2..+31 ----
            f32x16 sc;
            #pragma unroll
            for (int e = 0; e < 16; ++e) sc[e] = 0.f;
            #pragma unroll
            for (int kk = 0; kk < 4; ++kk) {
                const int row = 32*kt2 + li;
                s16x8 kf = *(const s16x8*)&Ks[cur][row*64 + 8*((hi + 2*kk) ^ (li & 7))];
                sc = MFMA32(kf, qf[kk], sc);
            }

            // ---- in-register softmax (lane owns q=li; keys in-lane + l^32) --
            float pmax = sc[0];
            #pragma unroll
            for (int r = 1; r < 16; ++r) pmax = fmaxf(pmax, sc[r]);
            pmax = fmaxf(pmax, __shfl_xor(pmax, 32, 64));

            if (__any((pmax > m + THR) ? 1 : 0)) {   // rare exact-rescale path
                const float mn = fmaxf(m, pmax);
                const float al = __builtin_amdgcn_exp2f((m - mn)*C);
                m = mn; ld *= al;
                xbuf[w][li] = al;
                #pragma unroll
                for (int j = 0; j < 4; ++j) {
                    f32x4 av = *(const f32x4*)&xbuf[w][8*j + 4*hi];
                    #pragma unroll
                    for (int rr = 0; rr < 4; ++rr) {
                        o[0][4*j + rr] *= av[rr];
                        o[1][4*j + rr] *= av[rr];
                    }
                }
            }

            const float nmC = -m*C;
            float p[16];
            float rsum = 0.f;
            #pragma unroll
            for (int r = 0; r < 16; ++r) {
                p[r] = __builtin_amdgcn_exp2f(fmaf(sc[r], C, nmC));
                rsum += p[r];
            }
            ld += rsum + __shfl_xor(rsum, 32, 64);

            // ---- P -> PV A-operand: cvt_pk pairs + permlane32_swap ----
            #pragma unroll
            for (int s2 = 0; s2 < 2; ++s2) {
                unsigned wa = cvtpk(p[8*s2 + 0], p[8*s2 + 1]);
                unsigned wb = cvtpk(p[8*s2 + 2], p[8*s2 + 3]);
                unsigned wc2 = cvtpk(p[8*s2 + 4], p[8*s2 + 5]);
                unsigned wd = cvtpk(p[8*s2 + 6], p[8*s2 + 7]);
                plswap(wa, wc2);
                plswap(wb, wd);
                u32x4 paw = {wa, wb, wc2, wd};
                s16x8 pa = __builtin_bit_cast(s16x8, paw);

                const int ks = 2*kt2 + s2;           // 16-key slice in tile
                #pragma unroll
                for (int dt = 0; dt < 2; ++dt) {
                    const int row = li + 32*dt;      // d-row of Vs
                    s16x8 vf = *(const s16x8*)&Vs[cur][row*64 + 8*((hi + 2*ks) ^ (li & 7))];
                    o[dt] = MFMA32(pa, vf, o[dt]);
                }
            }
        }
        asm volatile("s_waitcnt lgkmcnt(0)" ::: "memory");
        __builtin_amdgcn_s_barrier();
    }

    // ---- epilogue: transpose 1/ld across the lane<->reg layout, store ------
    xbuf[w][li] = ld;                          // l and l^32 write same value
    #pragma unroll
    for (int j = 0; j < 4; ++j) {
        f32x4 lv = *(const f32x4*)&xbuf[w][8*j + 4*hi];
        #pragma unroll
        for (int rr = 0; rr < 4; ++rr) {
            const int r  = 4*j + rr;
            const int qq = 8*j + 4*hi + rr;    // = (r&3)+8*(r>>2)+4*hi
            const int s  = qt*128 + w*32 + qq;
            const float inv = 1.0f / lv[rr];
            #pragma unroll
            for (int dt = 0; dt < 2; ++dt)
                attnb[((size_t)b*S_ + s)*D_ + h*HD_ + li + 32*dt] = f2b(o[dt][r]*inv);
        }
    }
}

extern "C" void kernel_launch(void* const* d_in, const int* in_sizes, int n_in,
                              void* d_out, int out_size, void* d_ws, size_t ws_size,
                              hipStream_t stream)
{
    const float* x  = (const float*)d_in[0];
    const float* Wq = (const float*)d_in[1];
    const float* Wk = (const float*)d_in[2];
    const float* Wv = (const float*)d_in[3];
    const float* Wo = (const float*)d_in[4];
    float* out = (float*)d_out;

    char* p = (char*)d_ws;
    unsigned short* xb    = (unsigned short*)p; p += (size_t)B_*S_*D_*2;
    unsigned short* wb    = (unsigned short*)p; p += (size_t)1536*1024*2;
    unsigned short* wob   = (unsigned short*)p; p += (size_t)1024*1024*2;
    unsigned short* qr    = (unsigned short*)p; p += (size_t)B_*H_*S_*HD_*2;
    unsigned short* kr    = (unsigned short*)p; p += (size_t)B_*G_*S_*HD_*2;
    unsigned short* vt    = (unsigned short*)p; p += (size_t)B_*G_*HD_*S_*2;
    unsigned short* attnb = (unsigned short*)p; p += (size_t)B_*S_*D_*2;
    float* cost = (float*)p; p += (size_t)S_*32*4;
    float* sint = (float*)p;

    prep_all<<<6720, 256, 0, stream>>>(x, Wq, Wk, Wv, Wo, xb, wb, wob, cost, sint);
    gemm_mfma<0><<<32*12, 256, 0, stream>>>(xb, wb, qr, kr, vt, nullptr, cost, sint, 12);
    flash_attn_mfma<<<B_*H_*(S_/128), 256, 0, stream>>>(qr, kr, vt, attnb);
    gemm_mfma<1><<<32*8, 256, 0, stream>>>(attnb, wob, nullptr, nullptr, nullptr, out, cost, sint, 8);
}

// Round 5
// 108.485 us; speedup vs baseline: 10.7140x; 1.0332x over previous
//
#include <hip/hip_runtime.h>
#include <hip/hip_bf16.h>
#include <math.h>

#define B_ 2
#define S_ 2048
#define D_ 1024
#define H_ 16
#define G_ 4
#define HD_ 64

typedef float f32x4  __attribute__((ext_vector_type(4)));
typedef float f32x16 __attribute__((ext_vector_type(16)));
typedef short s16x8  __attribute__((ext_vector_type(8)));
typedef unsigned short u16x4 __attribute__((ext_vector_type(4)));
typedef unsigned int   u32x4 __attribute__((ext_vector_type(4)));

__device__ __forceinline__ unsigned short f2b(float f) {
    __hip_bfloat16 h = __float2bfloat16(f);
    return __builtin_bit_cast(unsigned short, h);
}
__device__ __forceinline__ unsigned cvtpk(float lo, float hi) {
    unsigned r;
    asm("v_cvt_pk_bf16_f32 %0, %1, %2" : "=v"(r) : "v"(lo), "v"(hi));
    return r;
}
__device__ __forceinline__ void plswap(unsigned &a, unsigned &b) {
    asm("v_permlane32_swap_b32 %0, %1" : "+v"(a), "+v"(b));
}
__device__ __forceinline__ void plswapf(float &a, float &b) {
    unsigned ua = __builtin_bit_cast(unsigned, a);
    unsigned ub = __builtin_bit_cast(unsigned, b);
    plswap(ua, ub);
    a = __builtin_bit_cast(float, ua);
    b = __builtin_bit_cast(float, ub);
}

#define MFMA16(a, b, c) __builtin_amdgcn_mfma_f32_16x16x32_bf16(a, b, c, 0, 0, 0)
#define MFMA32(a, b, c) __builtin_amdgcn_mfma_f32_32x32x16_bf16(a, b, c, 0, 0, 0)

#define GLOAD16(gp, lp) __builtin_amdgcn_global_load_lds(                      \
    (const __attribute__((address_space(1))) void*)(gp),                      \
    (__attribute__((address_space(3))) void*)(lp), 16, 0, 0)

// ---------------- prep: bf16 casts + pooled K/V weights + rope tables -------
__global__ __launch_bounds__(256)
void prep_all(const float* __restrict__ x,  const float* __restrict__ Wq,
              const float* __restrict__ Wk, const float* __restrict__ Wv,
              const float* __restrict__ Wo,
              unsigned short* __restrict__ xb, unsigned short* __restrict__ wb,
              unsigned short* __restrict__ wob,
              float* __restrict__ cost, float* __restrict__ sint)
{
    const int NQ_WB = (1536*1024)/4;
    const int NQ_WO = (1024*1024)/4;
    const int NQ_X  = (B_*S_*D_)/4;
    int q = blockIdx.x*256 + threadIdx.x;
    if (q < NQ_WB) {
        const int idx = q*4, row = idx >> 10, c = idx & 1023;
        u16x4 o;
        if (row < 1024) {
            f32x4 v = *(const f32x4*)&Wq[(size_t)row*1024 + c];
            #pragma unroll
            for (int j = 0; j < 4; ++j) o[j] = f2b(v[j]);
        } else {
            const int rd = row - 1024, kv = rd >> 8, gd = rd & 255;
            const int g = gd >> 6, d = gd & 63;
            const float* W = kv ? Wv : Wk;
            f32x4 sum = {0.f, 0.f, 0.f, 0.f};
            #pragma unroll
            for (int p = 0; p < 4; ++p)
                sum += *(const f32x4*)&W[(size_t)((g*4 + p)*64 + d)*1024 + c];
            #pragma unroll
            for (int j = 0; j < 4; ++j) o[j] = f2b(sum[j]*0.25f);
        }
        *(u16x4*)&wb[idx] = o;
        return;
    }
    q -= NQ_WB;
    if (q < NQ_WO) {
        const int idx = q*4;
        f32x4 v = *(const f32x4*)&Wo[idx];
        u16x4 o;
        #pragma unroll
        for (int j = 0; j < 4; ++j) o[j] = f2b(v[j]);
        *(u16x4*)&wob[idx] = o;
        return;
    }
    q -= NQ_WO;
    if (q < NQ_X) {
        const int idx = q*4;
        f32x4 v = *(const f32x4*)&x[idx];
        u16x4 o;
        #pragma unroll
        for (int j = 0; j < 4; ++j) o[j] = f2b(v[j]);
        *(u16x4*)&xb[idx] = o;
        return;
    }
    q -= NQ_X;
    if (q < (S_*32)/4) {
        const int idx = q*4, s = idx >> 5, f0 = idx & 31;
        #pragma unroll
        for (int j = 0; j < 4; ++j) {
            const float f = (float)(f0 + j);
            const float fr = (float)s * powf(10000.0f, -f*(1.0f/32.0f));
            cost[idx + j] = cosf(fr);
            sint[idx + j] = sinf(fr);
        }
    }
}

// ---------------- MFMA GEMM: C = A(Mx1024) * B(Nx1024)^T, 128x128 tile ------
// MODE 0: fused QKV epilogue (bx<8: Q rope+permute; bx<10: K rope; else V^T)
// MODE 1: fp32 store (O-projection)
template<int MODE>
__global__ __launch_bounds__(256)
void gemm_mfma(const unsigned short* __restrict__ Am,
               const unsigned short* __restrict__ Bm,
               unsigned short* __restrict__ qr,
               unsigned short* __restrict__ kr,
               unsigned short* __restrict__ vt,
               float* __restrict__ outf,
               const float* __restrict__ cost,
               const float* __restrict__ sint,
               int nbx)
{
    __shared__ unsigned short As[2][128*64];
    __shared__ unsigned short Bs[2][128*64];

    const int nwg = gridDim.x;
    const int cpx = nwg >> 3;
    const int bid = blockIdx.x;
    const int swz = (bid & 7)*cpx + (bid >> 3);     // XCD-chunked (bijective)
    const int bx = swz % nbx, by = swz / nbx;

    const int t  = threadIdx.x;
    const int w  = t >> 6, l = t & 63;
    const int lg = l >> 4, lr = l & 15;
    const int wr = w >> 1, wc = w & 1;

    const unsigned short* gA = Am + (size_t)by*128*D_;
    const unsigned short* gB = Bm + (size_t)bx*128*D_;

    const int srow = l >> 3;
    const int schk = (l & 7) ^ srow;

#define STAGE(buf, k0)                                                         \
    _Pragma("unroll")                                                          \
    for (int i_ = 0; i_ < 4; ++i_) {                                           \
        const int row_ = 32*w + 8*i_ + srow;                                   \
        GLOAD16(gA + (size_t)row_*D_ + (k0) + 8*schk, &As[buf][(32*w + 8*i_)*64]); \
        GLOAD16(gB + (size_t)row_*D_ + (k0) + 8*schk, &Bs[buf][(32*w + 8*i_)*64]); \
    }

    f32x4 acc[4][4] = {};

    STAGE(0, 0);
    #pragma unroll 1
    for (int kt = 0; kt < 16; ++kt) {
        const int cur = kt & 1;
        if (kt < 15) {
            STAGE(cur ^ 1, 64*(kt + 1));
            asm volatile("s_waitcnt vmcnt(8)" ::: "memory");
        } else {
            asm volatile("s_waitcnt vmcnt(0)" ::: "memory");
        }
        __builtin_amdgcn_s_barrier();

        #pragma unroll
        for (int kk = 0; kk < 2; ++kk) {
            s16x8 af[4], bfr[4];
            #pragma unroll
            for (int m = 0; m < 4; ++m) {
                const int row = 64*wr + 16*m + lr;
                af[m] = *(const s16x8*)&As[cur][row*64 + 8*((lg + 4*kk) ^ (row & 7))];
            }
            #pragma unroll
            for (int n = 0; n < 4; ++n) {
                const int col = 64*wc + 16*n + lr;
                bfr[n] = *(const s16x8*)&Bs[cur][col*64 + 8*((lg + 4*kk) ^ (col & 7))];
            }
            #pragma unroll
            for (int m = 0; m < 4; ++m)
                #pragma unroll
                for (int n = 0; n < 4; ++n)
                    acc[m][n] = MFMA16(af[m], bfr[n], acc[m][n]);
        }
        asm volatile("s_waitcnt lgkmcnt(0)" ::: "memory");
        __builtin_amdgcn_s_barrier();
    }
#undef STAGE

    if (MODE == 1) {
        #pragma unroll
        for (int m = 0; m < 4; ++m)
            #pragma unroll
            for (int r = 0; r < 4; ++r) {
                const int row = by*128 + 64*wr + 16*m + 4*lg + r;
                #pragma unroll
                for (int n = 0; n < 4; ++n)
                    outf[(size_t)row*D_ + bx*128 + 64*wc + 16*n + lr] = acc[m][n][r];
            }
        return;
    }

    if (bx < 10) {   // Q (bx<8) or K (bx 8,9): rope; partner dd^32 = acc[m][n^2]
        #pragma unroll
        for (int m = 0; m < 4; ++m) {
            #pragma unroll
            for (int r = 0; r < 4; ++r) {
                const int row = by*128 + 64*wr + 16*m + 4*lg + r;
                const int b = row >> 11, s = row & (S_ - 1);
                const float c_lo = cost[s*32 + lr],      s_lo = sint[s*32 + lr];
                const float c_hi = cost[s*32 + 16 + lr], s_hi = sint[s*32 + 16 + lr];
                unsigned short vals[4];
                #pragma unroll
                for (int n = 0; n < 4; ++n) {
                    const float cc = (n & 1) ? c_hi : c_lo;
                    const float sn = (n & 1) ? s_hi : s_lo;
                    const float self = acc[m][n][r], part = acc[m][n ^ 2][r];
                    const float rv = (n < 2) ? fmaf(self, cc, -part*sn)
                                             : fmaf(self, cc,  part*sn);
                    vals[n] = f2b(rv);
                }
                size_t base;
                unsigned short* dst;
                if (bx < 8) {
                    const int hh = 2*bx + wc;
                    const int hp = (hh & 3)*4 + (hh >> 2);  // swapaxes(2,3)
                    base = (((size_t)b*H_ + hp)*S_ + s)*HD_;
                    dst = qr;
                } else {
                    const int g = (bx - 8)*2 + wc;
                    base = (((size_t)b*G_ + g)*S_ + s)*HD_;
                    dst = kr;
                }
                #pragma unroll
                for (int n = 0; n < 4; ++n) dst[base + 16*n + lr] = vals[n];
            }
        }
    } else {         // V: store transposed vt[b][g][dd][s]
        const int g = (bx - 10)*2 + wc;
        #pragma unroll
        for (int m = 0; m < 4; ++m) {
            const int row0 = by*128 + 64*wr + 16*m + 4*lg;
            const int b = row0 >> 11, s0 = row0 & (S_ - 1);
            #pragma unroll
            for (int n = 0; n < 4; ++n) {
                const int dd = 16*n + lr;
                u16x4 v;
                #pragma unroll
                for (int r = 0; r < 4; ++r) v[r] = f2b(acc[m][n][r]);
                *(u16x4*)&vt[(((size_t)b*G_ + g)*HD_ + dd)*S_ + s0] = v;
            }
        }
    }
}

// ---------------- MFMA flash attention, in-register softmax -----------------
// 4 waves x 32 q-rows, KVBLK=128 (16 phases), 32x32x16 MFMA, swapped QK^T.
// Per phase: 2 halves x {QK (2 indep MFMA chains) -> batched softmax (tree
// reductions, permlane32_swap cross-half) -> pack (cvt_pk+permlane) -> PV}.
__device__ __forceinline__ void stage128(const unsigned short* Kp, const unsigned short* Vp,
                                         unsigned short* ks, unsigned short* vs,
                                         int kt, int w, int l)
{
    const int srow = l >> 3;
    const int schk = (l & 7) ^ srow;
    const int vrow = l >> 4;
    #pragma unroll
    for (int i = 0; i < 4; ++i) {
        const int krow = 32*w + 8*i + srow;                       // LDS K row
        GLOAD16(Kp + ((size_t)(kt*128 + krow))*HD_ + 8*schk, ks + (32*w + 8*i)*64);
        const int d    = 16*w + 4*i + vrow;                       // LDS V row
        const int vchk = (l & 15) ^ (d & 7);
        GLOAD16(Vp + (size_t)d*S_ + kt*128 + 8*vchk, vs + (16*w + 4*i)*128);
    }
}

__global__ __launch_bounds__(256)
void flash_attn_mfma(const unsigned short* __restrict__ qr,
                     const unsigned short* __restrict__ kr,
                     const unsigned short* __restrict__ vt,
                     unsigned short* __restrict__ attnb)
{
    __shared__ unsigned short Ks[2][128*64];
    __shared__ unsigned short Vs[2][64*128];
    __shared__ float xbuf[4][32];

    const int nqt = S_/128;
    const int bid = blockIdx.x;
    const int cpx = gridDim.x >> 3;
    const int swz = (bid & 7)*cpx + (bid >> 3);
    const int qt = swz % nqt;
    const int h  = (swz/nqt) % H_;
    const int b  = swz/(nqt*H_);
    const int g  = h >> 2;
    const int t  = threadIdx.x;
    const int w  = t >> 6;
    const int l  = t & 63;
    const int hi = l >> 5;
    const int li = l & 31;

    const unsigned short* Qp = qr + (((size_t)b*H_ + h)*S_ + (size_t)qt*128 + w*32)*HD_;
    const unsigned short* Kp = kr + ((size_t)b*G_ + g)*(size_t)S_*HD_;
    const unsigned short* Vp = vt + ((size_t)b*G_ + g)*(size_t)HD_*S_;

    s16x8 qf[4];
    #pragma unroll
    for (int kk = 0; kk < 4; ++kk)
        qf[kk] = *(const s16x8*)(Qp + (size_t)li*HD_ + 16*kk + 8*hi);

    f32x16 o[2];
    #pragma unroll
    for (int dt = 0; dt < 2; ++dt)
        #pragma unroll
        for (int e = 0; e < 16; ++e) o[dt][e] = 0.f;
    float m = 0.f, ld = 0.f;

    const float C   = 0.18033688011112044f;   // (1/8)*log2(e)
    const float THR = 32.0f;
    const int   NT  = S_/128;

    stage128(Kp, Vp, Ks[0], Vs[0], 0, w, l);

    #pragma unroll 1
    for (int kt = 0; kt < NT; ++kt) {
        const int cur = kt & 1;
        if (kt + 1 < NT) {
            stage128(Kp, Vp, Ks[cur^1], Vs[cur^1], kt + 1, w, l);
            asm volatile("s_waitcnt vmcnt(8)" ::: "memory");
        } else {
            asm volatile("s_waitcnt vmcnt(0)" ::: "memory");
        }
        __builtin_amdgcn_s_barrier();

        #pragma unroll
        for (int half = 0; half < 2; ++half) {
            // ---- QK^T: two 32-key subtiles, independent MFMA chains ----
            f32x16 sc0, sc1;
            #pragma unroll
            for (int e = 0; e < 16; ++e) { sc0[e] = 0.f; sc1[e] = 0.f; }
            __builtin_amdgcn_s_setprio(1);
            #pragma unroll
            for (int kk = 0; kk < 4; ++kk) {
                const int chk = 8*((hi + 2*kk) ^ (li & 7));
                s16x8 kf0 = *(const s16x8*)&Ks[cur][(64*half      + li)*64 + chk];
                s16x8 kf1 = *(const s16x8*)&Ks[cur][(64*half + 32 + li)*64 + chk];
                sc0 = MFMA32(kf0, qf[kk], sc0);
                sc1 = MFMA32(kf1, qf[kk], sc1);
            }
            __builtin_amdgcn_s_setprio(0);

            // ---- batched max (tree) + defer-max check ----
            float mx[8];
            #pragma unroll
            for (int i = 0; i < 8; ++i)
                mx[i] = fmaxf(fmaxf(sc0[i], sc0[i+8]), fmaxf(sc1[i], sc1[i+8]));
            #pragma unroll
            for (int i = 0; i < 4; ++i) mx[i] = fmaxf(mx[i], mx[i+4]);
            float pmax = fmaxf(fmaxf(mx[0], mx[1]), fmaxf(mx[2], mx[3]));
            {
                float pa_ = pmax, pb_ = pmax;
                plswapf(pa_, pb_);
                pmax = fmaxf(pa_, pb_);
            }
            if (__any((pmax > m + THR) ? 1 : 0)) {   // rare exact-rescale path
                const float mn = fmaxf(m, pmax);
                const float al = __builtin_amdgcn_exp2f((m - mn)*C);
                m = mn; ld *= al;
                xbuf[w][li] = al;
                #pragma unroll
                for (int j = 0; j < 4; ++j) {
                    f32x4 av = *(const f32x4*)&xbuf[w][8*j + 4*hi];
                    #pragma unroll
                    for (int rr = 0; rr < 4; ++rr) {
                        o[0][4*j + rr] *= av[rr];
                        o[1][4*j + rr] *= av[rr];
                    }
                }
            }

            // ---- batched exps + tree sum + permlane cross-half ----
            const float nmC = -m*C;
            float p0[16], p1[16];
            #pragma unroll
            for (int r = 0; r < 16; ++r) {
                p0[r] = __builtin_amdgcn_exp2f(fmaf(sc0[r], C, nmC));
                p1[r] = __builtin_amdgcn_exp2f(fmaf(sc1[r], C, nmC));
            }
            float s8[8];
            #pragma unroll
            for (int i = 0; i < 8; ++i)
                s8[i] = (p0[i] + p0[i+8]) + (p1[i] + p1[i+8]);
            #pragma unroll
            for (int i = 0; i < 4; ++i) s8[i] += s8[i+4];
            float rsum = (s8[0] + s8[1]) + (s8[2] + s8[3]);
            {
                float ca = rsum, cb = rsum;
                plswapf(ca, cb);
                ld += ca + cb;
            }

            // ---- pack P (cvt_pk + permlane32_swap) + PV ----
            __builtin_amdgcn_s_setprio(1);
            #pragma unroll
            for (int s2 = 0; s2 < 2; ++s2) {
                unsigned a0 = cvtpk(p0[8*s2+0], p0[8*s2+1]);
                unsigned a1 = cvtpk(p0[8*s2+2], p0[8*s2+3]);
                unsigned a2 = cvtpk(p0[8*s2+4], p0[8*s2+5]);
                unsigned a3 = cvtpk(p0[8*s2+6], p0[8*s2+7]);
                plswap(a0, a2); plswap(a1, a3);
                u32x4 aw = {a0, a1, a2, a3};
                s16x8 paf = __builtin_bit_cast(s16x8, aw);
                const int ksA = 4*half + s2;
                #pragma unroll
                for (int dt = 0; dt < 2; ++dt) {
                    const int d = li + 32*dt;
                    s16x8 vf = *(const s16x8*)&Vs[cur][d*128 + 8*((hi + 2*ksA) ^ (li & 7))];
                    o[dt] = MFMA32(paf, vf, o[dt]);
                }
                unsigned b0 = cvtpk(p1[8*s2+0], p1[8*s2+1]);
                unsigned b1 = cvtpk(p1[8*s2+2], p1[8*s2+3]);
                unsigned b2 = cvtpk(p1[8*s2+4], p1[8*s2+5]);
                unsigned b3 = cvtpk(p1[8*s2+6], p1[8*s2+7]);
                plswap(b0, b2); plswap(b1, b3);
                u32x4 bw = {b0, b1, b2, b3};
                s16x8 pbf = __builtin_bit_cast(s16x8, bw);
                const int ksB = 4*half + 2 + s2;
                #pragma unroll
                for (int dt = 0; dt < 2; ++dt) {
                    const int d = li + 32*dt;
                    s16x8 vf = *(const s16x8*)&Vs[cur][d*128 + 8*((hi + 2*ksB) ^ (li & 7))];
                    o[dt] = MFMA32(pbf, vf, o[dt]);
                }
            }
            __builtin_amdgcn_s_setprio(0);
        }
        asm volatile("s_waitcnt lgkmcnt(0)" ::: "memory");
        __builtin_amdgcn_s_barrier();
    }

    // ---- epilogue: transpose 1/ld across the lane<->reg layout, store ------
    xbuf[w][li] = ld;                          // l and l^32 hold same value
    #pragma unroll
    for (int j = 0; j < 4; ++j) {
        f32x4 lv = *(const f32x4*)&xbuf[w][8*j + 4*hi];
        #pragma unroll
        for (int rr = 0; rr < 4; ++rr) {
            const int r  = 4*j + rr;
            const int qq = 8*j + 4*hi + rr;    // = (r&3)+8*(r>>2)+4*hi
            const int s  = qt*128 + w*32 + qq;
            const float inv = 1.0f / lv[rr];
            #pragma unroll
            for (int dt = 0; dt < 2; ++dt)
                attnb[((size_t)b*S_ + s)*D_ + h*HD_ + li + 32*dt] = f2b(o[dt][r]*inv);
        }
    }
}

extern "C" void kernel_launch(void* const* d_in, const int* in_sizes, int n_in,
                              void* d_out, int out_size, void* d_ws, size_t ws_size,
                              hipStream_t stream)
{
    const float* x  = (const float*)d_in[0];
    const float* Wq = (const float*)d_in[1];
    const float* Wk = (const float*)d_in[2];
    const float* Wv = (const float*)d_in[3];
    const float* Wo = (const float*)d_in[4];
    float* out = (float*)d_out;

    char* p = (char*)d_ws;
    unsigned short* xb    = (unsigned short*)p; p += (size_t)B_*S_*D_*2;
    unsigned short* wb    = (unsigned short*)p; p += (size_t)1536*1024*2;
    unsigned short* wob   = (unsigned short*)p; p += (size_t)1024*1024*2;
    unsigned short* qr    = (unsigned short*)p; p += (size_t)B_*H_*S_*HD_*2;
    unsigned short* kr    = (unsigned short*)p; p += (size_t)B_*G_*S_*HD_*2;
    unsigned short* vt    = (unsigned short*)p; p += (size_t)B_*G_*HD_*S_*2;
    unsigned short* attnb = (unsigned short*)p; p += (size_t)B_*S_*D_*2;
    float* cost = (float*)p; p += (size_t)S_*32*4;
    float* sint = (float*)p;

    prep_all<<<6720, 256, 0, stream>>>(x, Wq, Wk, Wv, Wo, xb, wb, wob, cost, sint);
    gemm_mfma<0><<<32*12, 256, 0, stream>>>(xb, wb, qr, kr, vt, nullptr, cost, sint, 12);
    flash_attn_mfma<<<B_*H_*(S_/128), 256, 0, stream>>>(qr, kr, vt, attnb);
    gemm_mfma<1><<<32*8, 256, 0, stream>>>(attnb, wob, nullptr, nullptr, nullptr, out, cost, sint, 8);
}

// Round 6
// 108.468 us; speedup vs baseline: 10.7156x; 1.0002x over previous
//
#include <hip/hip_runtime.h>
#include <hip/hip_bf16.h>
#include <math.h>

#define B_ 2
#define S_ 2048
#define D_ 1024
#define H_ 16
#define G_ 4
#define HD_ 64

typedef float f32x4  __attribute__((ext_vector_type(4)));
typedef float f32x16 __attribute__((ext_vector_type(16)));
typedef short s16x8  __attribute__((ext_vector_type(8)));
typedef unsigned short u16x4 __attribute__((ext_vector_type(4)));
typedef unsigned int   u32x4 __attribute__((ext_vector_type(4)));

__device__ __forceinline__ unsigned short f2b(float f) {
    __hip_bfloat16 h = __float2bfloat16(f);
    return __builtin_bit_cast(unsigned short, h);
}
__device__ __forceinline__ unsigned cvtpk(float lo, float hi) {
    unsigned r;
    asm("v_cvt_pk_bf16_f32 %0, %1, %2" : "=v"(r) : "v"(lo), "v"(hi));
    return r;
}
__device__ __forceinline__ void plswap(unsigned &a, unsigned &b) {
    asm("v_permlane32_swap_b32 %0, %1" : "+v"(a), "+v"(b));
}
__device__ __forceinline__ void plswapf(float &a, float &b) {
    unsigned ua = __builtin_bit_cast(unsigned, a);
    unsigned ub = __builtin_bit_cast(unsigned, b);
    plswap(ua, ub);
    a = __builtin_bit_cast(float, ua);
    b = __builtin_bit_cast(float, ub);
}

#define MFMA16(a, b, c) __builtin_amdgcn_mfma_f32_16x16x32_bf16(a, b, c, 0, 0, 0)
#define MFMA32(a, b, c) __builtin_amdgcn_mfma_f32_32x32x16_bf16(a, b, c, 0, 0, 0)

#define GLOAD16(gp, lp) __builtin_amdgcn_global_load_lds(                      \
    (const __attribute__((address_space(1))) void*)(gp),                      \
    (__attribute__((address_space(3))) void*)(lp), 16, 0, 0)

// ---------------- prep: bf16 casts + pooled K/V weights + rope tables -------
__global__ __launch_bounds__(256)
void prep_all(const float* __restrict__ x,  const float* __restrict__ Wq,
              const float* __restrict__ Wk, const float* __restrict__ Wv,
              const float* __restrict__ Wo,
              unsigned short* __restrict__ xb, unsigned short* __restrict__ wb,
              unsigned short* __restrict__ wob,
              float* __restrict__ cost, float* __restrict__ sint)
{
    const int NQ_WB = (1536*1024)/4;
    const int NQ_WO = (1024*1024)/4;
    const int NQ_X  = (B_*S_*D_)/4;
    int q = blockIdx.x*256 + threadIdx.x;
    if (q < NQ_WB) {
        const int idx = q*4, row = idx >> 10, c = idx & 1023;
        u16x4 o;
        if (row < 1024) {
            f32x4 v = *(const f32x4*)&Wq[(size_t)row*1024 + c];
            #pragma unroll
            for (int j = 0; j < 4; ++j) o[j] = f2b(v[j]);
        } else {
            const int rd = row - 1024, kv = rd >> 8, gd = rd & 255;
            const int g = gd >> 6, d = gd & 63;
            const float* W = kv ? Wv : Wk;
            f32x4 sum = {0.f, 0.f, 0.f, 0.f};
            #pragma unroll
            for (int p = 0; p < 4; ++p)
                sum += *(const f32x4*)&W[(size_t)((g*4 + p)*64 + d)*1024 + c];
            #pragma unroll
            for (int j = 0; j < 4; ++j) o[j] = f2b(sum[j]*0.25f);
        }
        *(u16x4*)&wb[idx] = o;
        return;
    }
    q -= NQ_WB;
    if (q < NQ_WO) {
        const int idx = q*4;
        f32x4 v = *(const f32x4*)&Wo[idx];
        u16x4 o;
        #pragma unroll
        for (int j = 0; j < 4; ++j) o[j] = f2b(v[j]);
        *(u16x4*)&wob[idx] = o;
        return;
    }
    q -= NQ_WO;
    if (q < NQ_X) {
        const int idx = q*4;
        f32x4 v = *(const f32x4*)&x[idx];
        u16x4 o;
        #pragma unroll
        for (int j = 0; j < 4; ++j) o[j] = f2b(v[j]);
        *(u16x4*)&xb[idx] = o;
        return;
    }
    q -= NQ_X;
    if (q < (S_*32)/4) {
        const int idx = q*4, s = idx >> 5, f0 = idx & 31;
        #pragma unroll
        for (int j = 0; j < 4; ++j) {
            const float f = (float)(f0 + j);
            const float fr = (float)s * powf(10000.0f, -f*(1.0f/32.0f));
            cost[idx + j] = cosf(fr);
            sint[idx + j] = sinf(fr);
        }
    }
}

// ---------------- MFMA GEMM: C = A(Mx1024) * B(Nx1024)^T, 128x128 tile ------
// MODE 0: fused QKV epilogue (bx<8: Q rope+permute; bx<10: K rope; else V^T)
// MODE 1: fp32 store (O-projection)
template<int MODE>
__global__ __launch_bounds__(256)
void gemm_mfma(const unsigned short* __restrict__ Am,
               const unsigned short* __restrict__ Bm,
               unsigned short* __restrict__ qr,
               unsigned short* __restrict__ kr,
               unsigned short* __restrict__ vt,
               float* __restrict__ outf,
               const float* __restrict__ cost,
               const float* __restrict__ sint,
               int nbx)
{
    __shared__ unsigned short As[2][128*64];
    __shared__ unsigned short Bs[2][128*64];

    const int nwg = gridDim.x;
    const int cpx = nwg >> 3;
    const int bid = blockIdx.x;
    const int swz = (bid & 7)*cpx + (bid >> 3);     // XCD-chunked (bijective)
    const int bx = swz % nbx, by = swz / nbx;

    const int t  = threadIdx.x;
    const int w  = t >> 6, l = t & 63;
    const int lg = l >> 4, lr = l & 15;
    const int wr = w >> 1, wc = w & 1;

    const unsigned short* gA = Am + (size_t)by*128*D_;
    const unsigned short* gB = Bm + (size_t)bx*128*D_;

    const int srow = l >> 3;
    const int schk = (l & 7) ^ srow;

#define STAGE(buf, k0)                                                         \
    _Pragma("unroll")                                                          \
    for (int i_ = 0; i_ < 4; ++i_) {                                           \
        const int row_ = 32*w + 8*i_ + srow;                                   \
        GLOAD16(gA + (size_t)row_*D_ + (k0) + 8*schk, &As[buf][(32*w + 8*i_)*64]); \
        GLOAD16(gB + (size_t)row_*D_ + (k0) + 8*schk, &Bs[buf][(32*w + 8*i_)*64]); \
    }

    f32x4 acc[4][4] = {};

    STAGE(0, 0);
    #pragma unroll 1
    for (int kt = 0; kt < 16; ++kt) {
        const int cur = kt & 1;
        if (kt < 15) {
            STAGE(cur ^ 1, 64*(kt + 1));
            asm volatile("s_waitcnt vmcnt(8)" ::: "memory");
        } else {
            asm volatile("s_waitcnt vmcnt(0)" ::: "memory");
        }
        __builtin_amdgcn_s_barrier();

        #pragma unroll
        for (int kk = 0; kk < 2; ++kk) {
            s16x8 af[4], bfr[4];
            #pragma unroll
            for (int m = 0; m < 4; ++m) {
                const int row = 64*wr + 16*m + lr;
                af[m] = *(const s16x8*)&As[cur][row*64 + 8*((lg + 4*kk) ^ (row & 7))];
            }
            #pragma unroll
            for (int n = 0; n < 4; ++n) {
                const int col = 64*wc + 16*n + lr;
                bfr[n] = *(const s16x8*)&Bs[cur][col*64 + 8*((lg + 4*kk) ^ (col & 7))];
            }
            #pragma unroll
            for (int m = 0; m < 4; ++m)
                #pragma unroll
                for (int n = 0; n < 4; ++n)
                    acc[m][n] = MFMA16(af[m], bfr[n], acc[m][n]);
        }
        asm volatile("s_waitcnt lgkmcnt(0)" ::: "memory");
        __builtin_amdgcn_s_barrier();
    }
#undef STAGE

    if (MODE == 1) {
        #pragma unroll
        for (int m = 0; m < 4; ++m)
            #pragma unroll
            for (int r = 0; r < 4; ++r) {
                const int row = by*128 + 64*wr + 16*m + 4*lg + r;
                #pragma unroll
                for (int n = 0; n < 4; ++n)
                    outf[(size_t)row*D_ + bx*128 + 64*wc + 16*n + lr] = acc[m][n][r];
            }
        return;
    }

    if (bx < 10) {   // Q (bx<8) or K (bx 8,9): rope; partner dd^32 = acc[m][n^2]
        #pragma unroll
        for (int m = 0; m < 4; ++m) {
            #pragma unroll
            for (int r = 0; r < 4; ++r) {
                const int row = by*128 + 64*wr + 16*m + 4*lg + r;
                const int b = row >> 11, s = row & (S_ - 1);
                const float c_lo = cost[s*32 + lr],      s_lo = sint[s*32 + lr];
                const float c_hi = cost[s*32 + 16 + lr], s_hi = sint[s*32 + 16 + lr];
                unsigned short vals[4];
                #pragma unroll
                for (int n = 0; n < 4; ++n) {
                    const float cc = (n & 1) ? c_hi : c_lo;
                    const float sn = (n & 1) ? s_hi : s_lo;
                    const float self = acc[m][n][r], part = acc[m][n ^ 2][r];
                    const float rv = (n < 2) ? fmaf(self, cc, -part*sn)
                                             : fmaf(self, cc,  part*sn);
                    vals[n] = f2b(rv);
                }
                size_t base;
                unsigned short* dst;
                if (bx < 8) {
                    const int hh = 2*bx + wc;
                    const int hp = (hh & 3)*4 + (hh >> 2);  // swapaxes(2,3)
                    base = (((size_t)b*H_ + hp)*S_ + s)*HD_;
                    dst = qr;
                } else {
                    const int g = (bx - 8)*2 + wc;
                    base = (((size_t)b*G_ + g)*S_ + s)*HD_;
                    dst = kr;
                }
                #pragma unroll
                for (int n = 0; n < 4; ++n) dst[base + 16*n + lr] = vals[n];
            }
        }
    } else {         // V: store transposed vt[b][g][dd][s]
        const int g = (bx - 10)*2 + wc;
        #pragma unroll
        for (int m = 0; m < 4; ++m) {
            const int row0 = by*128 + 64*wr + 16*m + 4*lg;
            const int b = row0 >> 11, s0 = row0 & (S_ - 1);
            #pragma unroll
            for (int n = 0; n < 4; ++n) {
                const int dd = 16*n + lr;
                u16x4 v;
                #pragma unroll
                for (int r = 0; r < 4; ++r) v[r] = f2b(acc[m][n][r]);
                *(u16x4*)&vt[(((size_t)b*G_ + g)*HD_ + dd)*S_ + s0] = v;
            }
        }
    }
}

// ---------------- MFMA flash attention, in-register softmax -----------------
// 4 waves x 32 q-rows, KVBLK=128 (16 phases), 32x32x16 MFMA, swapped QK^T.
// Per phase: 2 halves x {QK (2 indep MFMA chains) -> batched softmax (tree
// reductions, permlane32_swap cross-half) -> pack (cvt_pk+permlane) -> PV}.
__device__ __forceinline__ void stage128(const unsigned short* Kp, const unsigned short* Vp,
                                         unsigned short* ks, unsigned short* vs,
                                         int kt, int w, int l)
{
    const int srow = l >> 3;
    const int schk = (l & 7) ^ srow;
    const int vrow = l >> 4;
    #pragma unroll
    for (int i = 0; i < 4; ++i) {
        const int krow = 32*w + 8*i + srow;                       // LDS K row
        GLOAD16(Kp + ((size_t)(kt*128 + krow))*HD_ + 8*schk, ks + (32*w + 8*i)*64);
        const int d    = 16*w + 4*i + vrow;                       // LDS V row
        const int vchk = (l & 15) ^ (d & 7);
        GLOAD16(Vp + (size_t)d*S_ + kt*128 + 8*vchk, vs + (16*w + 4*i)*128);
    }
}

__global__ __launch_bounds__(256)
void flash_attn_mfma(const unsigned short* __restrict__ qr,
                     const unsigned short* __restrict__ kr,
                     const unsigned short* __restrict__ vt,
                     unsigned short* __restrict__ attnb)
{
    __shared__ unsigned short Ks[2][128*64];
    __shared__ unsigned short Vs[2][64*128];
    __shared__ float xbuf[4][32];

    const int nqt = S_/128;
    const int bid = blockIdx.x;
    const int cpx = gridDim.x >> 3;
    const int swz = (bid & 7)*cpx + (bid >> 3);
    const int qt = swz % nqt;
    const int h  = (swz/nqt) % H_;
    const int b  = swz/(nqt*H_);
    const int g  = h >> 2;
    const int t  = threadIdx.x;
    const int w  = t >> 6;
    const int l  = t & 63;
    const int hi = l >> 5;
    const int li = l & 31;

    const unsigned short* Qp = qr + (((size_t)b*H_ + h)*S_ + (size_t)qt*128 + w*32)*HD_;
    const unsigned short* Kp = kr + ((size_t)b*G_ + g)*(size_t)S_*HD_;
    const unsigned short* Vp = vt + ((size_t)b*G_ + g)*(size_t)HD_*S_;

    s16x8 qf[4];
    #pragma unroll
    for (int kk = 0; kk < 4; ++kk)
        qf[kk] = *(const s16x8*)(Qp + (size_t)li*HD_ + 16*kk + 8*hi);

    f32x16 o[2];
    #pragma unroll
    for (int dt = 0; dt < 2; ++dt)
        #pragma unroll
        for (int e = 0; e < 16; ++e) o[dt][e] = 0.f;
    float m = 0.f, ld = 0.f;

    const float C   = 0.18033688011112044f;   // (1/8)*log2(e)
    const float THR = 32.0f;
    const int   NT  = S_/128;

    stage128(Kp, Vp, Ks[0], Vs[0], 0, w, l);

    #pragma unroll 1
    for (int kt = 0; kt < NT; ++kt) {
        const int cur = kt & 1;
        if (kt + 1 < NT) {
            stage128(Kp, Vp, Ks[cur^1], Vs[cur^1], kt + 1, w, l);
            asm volatile("s_waitcnt vmcnt(8)" ::: "memory");
        } else {
            asm volatile("s_waitcnt vmcnt(0)" ::: "memory");
        }
        __builtin_amdgcn_s_barrier();

        #pragma unroll
        for (int half = 0; half < 2; ++half) {
            // ---- QK^T: two 32-key subtiles, independent MFMA chains ----
            f32x16 sc0, sc1;
            #pragma unroll
            for (int e = 0; e < 16; ++e) { sc0[e] = 0.f; sc1[e] = 0.f; }
            __builtin_amdgcn_s_setprio(1);
            #pragma unroll
            for (int kk = 0; kk < 4; ++kk) {
                const int chk = 8*((hi + 2*kk) ^ (li & 7));
                s16x8 kf0 = *(const s16x8*)&Ks[cur][(64*half      + li)*64 + chk];
                s16x8 kf1 = *(const s16x8*)&Ks[cur][(64*half + 32 + li)*64 + chk];
                sc0 = MFMA32(kf0, qf[kk], sc0);
                sc1 = MFMA32(kf1, qf[kk], sc1);
            }
            __builtin_amdgcn_s_setprio(0);

            // ---- batched max (tree) + defer-max check ----
            float mx[8];
            #pragma unroll
            for (int i = 0; i < 8; ++i)
                mx[i] = fmaxf(fmaxf(sc0[i], sc0[i+8]), fmaxf(sc1[i], sc1[i+8]));
            #pragma unroll
            for (int i = 0; i < 4; ++i) mx[i] = fmaxf(mx[i], mx[i+4]);
            float pmax = fmaxf(fmaxf(mx[0], mx[1]), fmaxf(mx[2], mx[3]));
            {
                float pa_ = pmax, pb_ = pmax;
                plswapf(pa_, pb_);
                pmax = fmaxf(pa_, pb_);
            }
            if (__any((pmax > m + THR) ? 1 : 0)) {   // rare exact-rescale path
                const float mn = fmaxf(m, pmax);
                const float al = __builtin_amdgcn_exp2f((m - mn)*C);
                m = mn; ld *= al;
                xbuf[w][li] = al;
                #pragma unroll
                for (int j = 0; j < 4; ++j) {
                    f32x4 av = *(const f32x4*)&xbuf[w][8*j + 4*hi];
                    #pragma unroll
                    for (int rr = 0; rr < 4; ++rr) {
                        o[0][4*j + rr] *= av[rr];
                        o[1][4*j + rr] *= av[rr];
                    }
                }
            }

            // ---- batched exps + tree sum + permlane cross-half ----
            const float nmC = -m*C;
            float p0[16], p1[16];
            #pragma unroll
            for (int r = 0; r < 16; ++r) {
                p0[r] = __builtin_amdgcn_exp2f(fmaf(sc0[r], C, nmC));
                p1[r] = __builtin_amdgcn_exp2f(fmaf(sc1[r], C, nmC));
            }
            float s8[8];
            #pragma unroll
            for (int i = 0; i < 8; ++i)
                s8[i] = (p0[i] + p0[i+8]) + (p1[i] + p1[i+8]);
            #pragma unroll
            for (int i = 0; i < 4; ++i) s8[i] += s8[i+4];
            float rsum = (s8[0] + s8[1]) + (s8[2] + s8[3]);
            {
                float ca = rsum, cb = rsum;
                plswapf(ca, cb);
                ld += ca + cb;
            }

            // ---- pack P (cvt_pk + permlane32_swap) + PV ----
            __builtin_amdgcn_s_setprio(1);
            #pragma unroll
            for (int s2 = 0; s2 < 2; ++s2) {
                unsigned a0 = cvtpk(p0[8*s2+0], p0[8*s2+1]);
                unsigned a1 = cvtpk(p0[8*s2+2], p0[8*s2+3]);
                unsigned a2 = cvtpk(p0[8*s2+4], p0[8*s2+5]);
                unsigned a3 = cvtpk(p0[8*s2+6], p0[8*s2+7]);
                plswap(a0, a2); plswap(a1, a3);
                u32x4 aw = {a0, a1, a2, a3};
                s16x8 paf = __builtin_bit_cast(s16x8, aw);
                const int ksA = 4*half + s2;
                #pragma unroll
                for (int dt = 0; dt < 2; ++dt) {
                    const int d = li + 32*dt;
                    s16x8 vf = *(const s16x8*)&Vs[cur][d*128 + 8*((hi + 2*ksA) ^ (li & 7))];
                    o[dt] = MFMA32(paf, vf, o[dt]);
                }
                unsigned b0 = cvtpk(p1[8*s2+0], p1[8*s2+1]);
                unsigned b1 = cvtpk(p1[8*s2+2], p1[8*s2+3]);
                unsigned b2 = cvtpk(p1[8*s2+4], p1[8*s2+5]);
                unsigned b3 = cvtpk(p1[8*s2+6], p1[8*s2+7]);
                plswap(b0, b2); plswap(b1, b3);
                u32x4 bw = {b0, b1, b2, b3};
                s16x8 pbf = __builtin_bit_cast(s16x8, bw);
                const int ksB = 4*half + 2 + s2;
                #pragma unroll
                for (int dt = 0; dt < 2; ++dt) {
                    const int d = li + 32*dt;
                    s16x8 vf = *(const s16x8*)&Vs[cur][d*128 + 8*((hi + 2*ksB) ^ (li & 7))];
                    o[dt] = MFMA32(pbf, vf, o[dt]);
                }
            }
            __builtin_amdgcn_s_setprio(0);
        }
        asm volatile("s_waitcnt lgkmcnt(0)" ::: "memory");
        __builtin_amdgcn_s_barrier();
    }

    // ---- epilogue: transpose 1/ld across the lane<->reg layout, store ------
    xbuf[w][li] = ld;                          // l and l^32 hold same value
    #pragma unroll
    for (int j = 0; j < 4; ++j) {
        f32x4 lv = *(const f32x4*)&xbuf[w][8*j + 4*hi];
        #pragma unroll
        for (int rr = 0; rr < 4; ++rr) {
            const int r  = 4*j + rr;
            const int qq = 8*j + 4*hi + rr;    // = (r&3)+8*(r>>2)+4*hi
            const int s  = qt*128 + w*32 + qq;
            const float inv = 1.0f / lv[rr];
            #pragma unroll
            for (int dt = 0; dt < 2; ++dt)
                attnb[((size_t)b*S_ + s)*D_ + h*HD_ + li + 32*dt] = f2b(o[dt][r]*inv);
        }
    }
}

extern "C" void kernel_launch(void* const* d_in, const int* in_sizes, int n_in,
                              void* d_out, int out_size, void* d_ws, size_t ws_size,
                              hipStream_t stream)
{
    const float* x  = (const float*)d_in[0];
    const float* Wq = (const float*)d_in[1];
    const float* Wk = (const float*)d_in[2];
    const float* Wv = (const float*)d_in[3];
    const float* Wo = (const float*)d_in[4];
    float* out = (float*)d_out;

    char* p = (char*)d_ws;
    unsigned short* xb    = (unsigned short*)p; p += (size_t)B_*S_*D_*2;
    unsigned short* wb    = (unsigned short*)p; p += (size_t)1536*1024*2;
    unsigned short* wob   = (unsigned short*)p; p += (size_t)1024*1024*2;
    unsigned short* qr    = (unsigned short*)p; p += (size_t)B_*H_*S_*HD_*2;
    unsigned short* kr    = (unsigned short*)p; p += (size_t)B_*G_*S_*HD_*2;
    unsigned short* vt    = (unsigned short*)p; p += (size_t)B_*G_*HD_*S_*2;
    unsigned short* attnb = (unsigned short*)p; p += (size_t)B_*S_*D_*2;
    float* cost = (float*)p; p += (size_t)S_*32*4;
    float* sint = (float*)p;

    prep_all<<<6720, 256, 0, stream>>>(x, Wq, Wk, Wv, Wo, xb, wb, wob, cost, sint);
    gemm_mfma<0><<<32*12, 256, 0, stream>>>(xb, wb, qr, kr, vt, nullptr, cost, sint, 12);
    flash_attn_mfma<<<B_*H_*(S_/128), 256, 0, stream>>>(qr, kr, vt, attnb);
    gemm_mfma<1><<<32*8, 256, 0, stream>>>(attnb, wob, nullptr, nullptr, nullptr, out, cost, sint, 8);
}